// Round 1
// baseline (2083.003 us; speedup 1.0000x reference)
//
#include <hip/hip_runtime.h>

// CrossScaleAttention on MI355X — fused flash-attention formulation.
//
// Reference == attention: per sample b,
//   Q[p]  = 3x3x32 patch of match_input (9216 queries, d=288)
//   K[l]  = 3x3x32 patch of ref, logits = 10 * (Q.Kraw) / max(||Kraw||,1e-4)
//   A     = softmax over 2304 keys
//   V[l]  = 3x3x64 patch of embed_w (d_v=576)
//   out   = stride-2 overlap-add scatter of (A@V)/6 into [64,191,191] (atomics)
//
// Precision: score GEMM uses bf16 hi/lo split of both operands
// (Qhi*Khi + Qhi*Klo + Qlo*Khi) => logits are ~fp32-exact; only P and V are
// single-bf16 quantized (error floor ~1e-3 << 8e-3 threshold).
//
// Workspace layout (19,410,944 B total):
//   xcl_hi/lo : [4][98][98][32] bf16 channels-last match_input, zero halo
//   rcl_hi/lo : [4][50][50][32] bf16 channels-last ref, zero halo
//   ef32      : [4][50][50][64] f32 channels-last embed_w, zero halo
//   vtp       : [4][576][2304] bf16  V^T  (n = tap*64 + c, l = ly*48+lx)
//   invn      : [4][2304] f32  10 / max(norm_l, 1e-4)

typedef unsigned short u16;
typedef __attribute__((ext_vector_type(8))) short short8;   // 8 bf16 = 4 VGPR
typedef __attribute__((ext_vector_type(4))) float f32x4;

__device__ __forceinline__ u16 f2bf(float f) {
    unsigned u = __float_as_uint(f);
    unsigned r = (u + 0x7FFFu + ((u >> 16) & 1u)) >> 16;   // RNE
    return (u16)r;
}
__device__ __forceinline__ float bf2f(u16 h) {
    return __uint_as_float(((unsigned)h) << 16);
}
__device__ __forceinline__ short8 ld8(const u16* p) {
    return *(const short8*)p;
}

// ---------------------------------------------------------------- zero fill
__global__ void kzero(float4* p, long n) {
    long i = (long)blockIdx.x * blockDim.x + threadIdx.x;
    long st = (long)gridDim.x * blockDim.x;
    float4 z; z.x = 0.f; z.y = 0.f; z.z = 0.f; z.w = 0.f;
    for (; i < n; i += st) p[i] = z;
}

// ------------------------------------------------- match_input -> xcl hi/lo
// one block per (b, y): conv1x1(64->32) + PReLU, split to bf16 hi/lo.
__global__ void kmatch(const float* __restrict__ input, const float* __restrict__ w1,
                       const float* __restrict__ b1, const float* __restrict__ a1,
                       u16* __restrict__ xhi, u16* __restrict__ xlo) {
    __shared__ float xl[64 * 96];
    __shared__ float wl[32 * 65];   // +1 pad: kills 32-way bank conflict
    int b = blockIdx.x / 96, y = blockIdx.x % 96;
    int tid = threadIdx.x;
    for (int i = tid; i < 64 * 96; i += 256) {
        int ci = i / 96, xx = i % 96;
        xl[i] = input[(((b * 64 + ci) * 96) + y) * 96 + xx];
    }
    for (int i = tid; i < 2048; i += 256) wl[(i >> 6) * 65 + (i & 63)] = w1[i];
    __syncthreads();
    float aa = a1[0];
    for (int o = tid; o < 96 * 32; o += 256) {
        int xx = o >> 5, c = o & 31;
        float acc = b1[c];
        #pragma unroll
        for (int ci = 0; ci < 64; ci++) acc = fmaf(xl[ci * 96 + xx], wl[c * 65 + ci], acc);
        float v = acc >= 0.f ? acc : aa * acc;
        u16 hi = f2bf(v);
        float lo = v - bf2f(hi);
        int idx = ((b * 98 + y + 1) * 98 + (xx + 1)) * 32 + c;
        xhi[idx] = hi; xlo[idx] = f2bf(lo);
    }
}

// ------------------------------- small -> ef32 (embed, f32) + rcl hi/lo (ref)
__global__ void ksmall(const float* __restrict__ small, const float* __restrict__ wasm,
                       const float* __restrict__ basm, const float* __restrict__ aasm,
                       const float* __restrict__ wm2, const float* __restrict__ bm2,
                       const float* __restrict__ am2,
                       float* __restrict__ ef32, u16* __restrict__ rhi, u16* __restrict__ rlo) {
    __shared__ float sl[64 * 48];
    __shared__ float wa[64 * 65];
    __shared__ float wm[32 * 65];
    int b = blockIdx.x / 48, y = blockIdx.x % 48;
    int tid = threadIdx.x;
    for (int i = tid; i < 64 * 48; i += 256) {
        int ci = i / 48, xx = i % 48;
        sl[i] = small[(((b * 64 + ci) * 48) + y) * 48 + xx];
    }
    for (int i = tid; i < 4096; i += 256) wa[(i >> 6) * 65 + (i & 63)] = wasm[i];
    for (int i = tid; i < 2048; i += 256) wm[(i >> 6) * 65 + (i & 63)] = wm2[i];
    __syncthreads();
    float ae = aasm[0], ar = am2[0];
    for (int o = tid; o < 48 * 64; o += 256) {            // embed_w
        int xx = o >> 6, c = o & 63;
        float acc = basm[c];
        #pragma unroll
        for (int ci = 0; ci < 64; ci++) acc = fmaf(sl[ci * 48 + xx], wa[c * 65 + ci], acc);
        float v = acc >= 0.f ? acc : ae * acc;
        ef32[((b * 50 + y + 1) * 50 + (xx + 1)) * 64 + c] = v;
    }
    for (int o = tid; o < 48 * 32; o += 256) {            // ref
        int xx = o >> 5, c = o & 31;
        float acc = bm2[c];
        #pragma unroll
        for (int ci = 0; ci < 64; ci++) acc = fmaf(sl[ci * 48 + xx], wm[c * 65 + ci], acc);
        float v = acc >= 0.f ? acc : ar * acc;
        u16 hi = f2bf(v);
        float lo = v - bf2f(hi);
        int idx = ((b * 50 + y + 1) * 50 + (xx + 1)) * 32 + c;
        rhi[idx] = hi; rlo[idx] = f2bf(lo);
    }
}

// ------------------------------------------------------------ invnorm per key
__global__ void kinvnorm(const u16* __restrict__ rhi, const u16* __restrict__ rlo,
                         float* __restrict__ invn) {
    int idx = blockIdx.x * 256 + threadIdx.x;   // 9216 exact
    int b = idx / 2304, l = idx % 2304;
    int ly = l / 48, lx = l % 48;
    float s = 0.f;
    for (int ty = 0; ty < 3; ty++)
        for (int tx = 0; tx < 3; tx++) {
            int base = ((b * 50 + ly + ty) * 50 + (lx + tx)) * 32;
            #pragma unroll
            for (int c = 0; c < 32; c++) {
                float v = bf2f(rhi[base + c]) + bf2f(rlo[base + c]);
                s = fmaf(v, v, s);
            }
        }
    invn[idx] = 10.f / fmaxf(sqrtf(s), 1e-4f);   // SCALE folded in
}

// ------------------------------------------------------------- pack V^T bf16
__global__ void kvtp(const float* __restrict__ ef32, u16* __restrict__ vtp) {
    const int N = 4 * 576 * 2304;
    int st = gridDim.x * blockDim.x;
    for (int i = blockIdx.x * blockDim.x + threadIdx.x; i < N; i += st) {
        int b = i / (576 * 2304);
        int rem = i % (576 * 2304);
        int n = rem / 2304, l = rem % 2304;
        int t = n >> 6, c = n & 63;
        int ly = l / 48 + t / 3, lx = l % 48 + t % 3;
        vtp[i] = f2bf(ef32[((b * 50 + ly) * 50 + lx) * 64 + c]);
    }
}

// ------------------------------------------------------------- fused flash
// grid = 4*144; block = 256 (4 waves). BM=64 queries (16 px x 4 py, wave w
// owns row py0+w for the score phase => softmax stats stay inside the wave),
// BN=96 keys (2 key rows). P round-trips through LDS (row stride 104 to
// avoid 8-way bank conflicts on ds_read_b128).
__launch_bounds__(256, 2)
__global__ void kflash(const u16* __restrict__ xhi, const u16* __restrict__ xlo,
                       const u16* __restrict__ rhi, const u16* __restrict__ rlo,
                       const u16* __restrict__ vtp, const float* __restrict__ invn,
                       float* __restrict__ out) {
    __shared__ u16 Pl[64 * 104];
    __shared__ float alds[64];
    __shared__ float llds[64];

    int tid = threadIdx.x;
    int w = tid >> 6, lane = tid & 63;
    int l15 = lane & 15, quad = lane >> 4;
    int wg = blockIdx.x;
    int b = wg / 144, t = wg % 144;
    int px0 = (t % 6) * 16, py0 = (t / 6) * 4;

    const u16* xh = xhi + (size_t)b * 98 * 98 * 32;
    const u16* xl_ = xlo + (size_t)b * 98 * 98 * 32;
    const u16* rh = rhi + (size_t)b * 50 * 50 * 32;
    const u16* rl = rlo + (size_t)b * 50 * 50 * 32;
    const float* invb = invn + b * 2304;
    int aoff = ((py0 + w) * 98 + (px0 + l15)) * 32 + quad * 8;
    int boff = l15 * 32 + quad * 8;
    const u16* vbase = vtp + (size_t)b * 576 * 2304 + (size_t)(w * 144 + l15) * 2304 + quad * 8;

    f32x4 acc[36];
    #pragma unroll
    for (int i = 0; i < 36; i++) acc[i] = (f32x4)0.f;
    float m_run[4], l_run[4];
    #pragma unroll
    for (int r = 0; r < 4; r++) { m_run[r] = -1e30f; l_run[r] = 0.f; }

    for (int ly0 = 0; ly0 < 48; ly0 += 2) {
        // ---- score phase: S[16 rows(px), 96 keys], K-dim 864 = 3 phases x 9 taps x 32c
        f32x4 sf[6];
        #pragma unroll
        for (int i = 0; i < 6; i++) sf[i] = (f32x4)0.f;
        #pragma unroll
        for (int ph = 0; ph < 3; ph++) {
            const u16* xa = (ph == 2 ? xl_ : xh) + aoff;
            const u16* rb = (ph == 1 ? rl : rh) + boff + ly0 * (50 * 32);
            #pragma unroll
            for (int ty = 0; ty < 3; ty++) {
                #pragma unroll
                for (int tx = 0; tx < 3; tx++) {
                    short8 a = ld8(xa + (ty * 98 + tx) * 32);
                    #pragma unroll
                    for (int nt = 0; nt < 6; nt++) {
                        const int lyo = nt / 3, lxo = nt % 3;
                        short8 bb = ld8(rb + ((lyo + ty) * 50 + lxo * 16 + tx) * 32);
                        sf[nt] = __builtin_amdgcn_mfma_f32_16x16x32_bf16(a, bb, sf[nt], 0, 0, 0);
                    }
                }
            }
        }
        // ---- online softmax (rows owned by this wave; cols spread over l15)
        float invs[6];
        #pragma unroll
        for (int nt = 0; nt < 6; nt++)
            invs[nt] = invb[(ly0 + nt / 3) * 48 + (nt % 3) * 16 + l15];
        float mnew[4], al[4];
        #pragma unroll
        for (int r = 0; r < 4; r++) {
            float mx = -1e30f;
            #pragma unroll
            for (int nt = 0; nt < 6; nt++) mx = fmaxf(mx, sf[nt][r] * invs[nt]);
            mx = fmaxf(mx, __shfl_xor(mx, 1));
            mx = fmaxf(mx, __shfl_xor(mx, 2));
            mx = fmaxf(mx, __shfl_xor(mx, 4));
            mx = fmaxf(mx, __shfl_xor(mx, 8));
            mnew[r] = fmaxf(m_run[r], mx);
            al[r] = __expf(m_run[r] - mnew[r]);
        }
        float pv[6][4];
        #pragma unroll
        for (int nt = 0; nt < 6; nt++)
            #pragma unroll
            for (int r = 0; r < 4; r++)
                pv[nt][r] = __expf(sf[nt][r] * invs[nt] - mnew[r]);
        #pragma unroll
        for (int r = 0; r < 4; r++) {
            float s = pv[0][r] + pv[1][r] + pv[2][r] + pv[3][r] + pv[4][r] + pv[5][r];
            s += __shfl_xor(s, 1);
            s += __shfl_xor(s, 2);
            s += __shfl_xor(s, 4);
            s += __shfl_xor(s, 8);
            l_run[r] = l_run[r] * al[r] + s;
            m_run[r] = mnew[r];
        }
        int prow = w * 16 + quad * 4;
        #pragma unroll
        for (int nt = 0; nt < 6; nt++) {
            int kloc = (nt / 3) * 48 + (nt % 3) * 16 + l15;
            #pragma unroll
            for (int r = 0; r < 4; r++) Pl[(prow + r) * 104 + kloc] = f2bf(pv[nt][r]);
        }
        if (l15 == 0) {
            #pragma unroll
            for (int r = 0; r < 4; r++) alds[prow + r] = al[r];
        }
        __syncthreads();

        // ---- rescale O by alpha (skip when all alphas == 1)
        float ar[4][4];
        bool need = false;
        #pragma unroll
        for (int mt = 0; mt < 4; mt++)
            #pragma unroll
            for (int r = 0; r < 4; r++) {
                ar[mt][r] = alds[mt * 16 + quad * 4 + r];
                need |= (ar[mt][r] != 1.0f);
            }
        if (__any(need)) {
            #pragma unroll
            for (int mt = 0; mt < 4; mt++)
                #pragma unroll
                for (int nt = 0; nt < 9; nt++)
                    #pragma unroll
                    for (int r = 0; r < 4; r++) acc[mt * 9 + nt][r] *= ar[mt][r];
        }
        // ---- PV: O[64 rows, this wave's 144 v-cols] += P[64,96] @ V[96,144]
        const u16* vb = vbase + ly0 * 48;
        #pragma unroll
        for (int ks = 0; ks < 3; ks++) {
            short8 pa[4];
            #pragma unroll
            for (int mt = 0; mt < 4; mt++)
                pa[mt] = ld8(&Pl[(mt * 16 + l15) * 104 + ks * 32 + quad * 8]);
            #pragma unroll
            for (int nt = 0; nt < 9; nt++) {
                short8 vv = ld8(vb + nt * 16 * 2304 + ks * 32);
                #pragma unroll
                for (int mt = 0; mt < 4; mt++)
                    acc[mt * 9 + nt] = __builtin_amdgcn_mfma_f32_16x16x32_bf16(pa[mt], vv, acc[mt * 9 + nt], 0, 0, 0);
            }
        }
        __syncthreads();   // before next iteration overwrites Pl
    }

    // ---- epilogue: /l, /6, overlap-add scatter (conv_transpose stride 2, pad 1)
    int prow = w * 16 + quad * 4;
    if (l15 == 0) {
        #pragma unroll
        for (int r = 0; r < 4; r++) llds[prow + r] = l_run[r];
    }
    __syncthreads();
    float rl_[4][4];
    #pragma unroll
    for (int mt = 0; mt < 4; mt++)
        #pragma unroll
        for (int r = 0; r < 4; r++) rl_[mt][r] = 1.0f / (llds[mt * 16 + quad * 4 + r] * 6.0f);

    float* ob = out + (size_t)b * 64 * 191 * 191;
    #pragma unroll
    for (int nt = 0; nt < 9; nt++) {
        int n = w * 144 + nt * 16 + l15;
        int tt = n >> 6, c = n & 63;
        int ty = tt / 3, tx = tt % 3;
        float* oc = ob + c * (191 * 191);
        #pragma unroll
        for (int mt = 0; mt < 4; mt++) {
            int py = py0 + mt;
            int oy = 2 * py + ty - 1;
            #pragma unroll
            for (int r = 0; r < 4; r++) {
                int px = px0 + quad * 4 + r;
                int ox = 2 * px + tx - 1;
                if ((unsigned)oy < 191u && (unsigned)ox < 191u)
                    atomicAdd(&oc[oy * 191 + ox], acc[mt * 9 + nt][r] * rl_[mt][r]);
            }
        }
    }
}

// --------------------------------------------------------------------- host
extern "C" void kernel_launch(void* const* d_in, const int* in_sizes, int n_in,
                              void* d_out, int out_size, void* d_ws, size_t ws_size,
                              hipStream_t stream) {
    const float* input = (const float*)d_in[0];
    const float* small = (const float*)d_in[1];
    const float* w1 = (const float*)d_in[2];
    const float* b1 = (const float*)d_in[3];
    const float* a1 = (const float*)d_in[4];
    const float* w2 = (const float*)d_in[5];
    const float* b2 = (const float*)d_in[6];
    const float* a2 = (const float*)d_in[7];
    const float* wa = (const float*)d_in[8];
    const float* ba = (const float*)d_in[9];
    const float* aa = (const float*)d_in[10];

    char* ws = (char*)d_ws;
    u16* xhi = (u16*)(ws + 0);            // 2,458,624 B
    u16* xlo = (u16*)(ws + 2458624);      // 2,458,624 B
    u16* rhi = (u16*)(ws + 4917248);      //   640,000 B
    u16* rlo = (u16*)(ws + 5557248);      //   640,000 B
    float* ef = (float*)(ws + 6197248);   // 2,560,000 B
    u16* vtp = (u16*)(ws + 8757248);      // 10,616,832 B
    float* invn = (float*)(ws + 19374080);//    36,864 B  -> total 19,410,944 B
    float* out = (float*)d_out;

    // zero halo'd staging region + output (poisoned with 0xAA before each call)
    kzero<<<1024, 256, 0, stream>>>((float4*)ws, 8757248 / 16);
    kzero<<<1024, 256, 0, stream>>>((float4*)out, 37356544 / 16);
    kmatch<<<384, 256, 0, stream>>>(input, w1, b1, a1, xhi, xlo);
    ksmall<<<192, 256, 0, stream>>>(small, wa, ba, aa, w2, b2, a2, ef, rhi, rlo);
    kinvnorm<<<36, 256, 0, stream>>>(rhi, rlo, invn);
    kvtp<<<2048, 256, 0, stream>>>(ef, vtp);
    kflash<<<576, 256, 0, stream>>>(xhi, xlo, rhi, rlo, vtp, invn, out);
}

// Round 2
// 1039.647 us; speedup vs baseline: 2.0036x; 2.0036x over previous
//
#include <hip/hip_runtime.h>

// CrossScaleAttention on MI355X — round 2.
// R1 post-mortem: latency-bound (MfmaUtil 5%), atomic epilogue caused 2.26 GB
// HBM writes. R2: LDS-staged Q/K for the score GEMM, Z-materialized epilogue
// (no atomics) + parity-stencil gather kernel, XCD-aware block swizzle.
//
// Workspace layout (105,625,600 B total):
//   xhi/xlo : [4][98][98][32] bf16 channels-last match_input (hi/lo split), zero halo
//   rkl     : [4][50][2][50][32] bf16 ref, hi/lo interleaved per row, zero halo
//   ef32    : [4][50][50][64] f32 embed_w, zero halo
//   vtp     : [4][576][2304] bf16  V^T  (n = tap*64 + c, l = ly*48+lx)
//   invn    : [4][2304] f32  10 / max(norm_l, 1e-4)
//   Z       : [4][9216][576] f32  (A@V)/(6*l)  -- gather input
// Fallback (ws too small): atomic epilogue directly to out (R1 style).

typedef unsigned short u16;
typedef __attribute__((ext_vector_type(8))) short short8;   // 8 bf16 = 4 VGPR
typedef __attribute__((ext_vector_type(4))) float f32x4;

__device__ __forceinline__ u16 f2bf(float f) {
    unsigned u = __float_as_uint(f);
    unsigned r = (u + 0x7FFFu + ((u >> 16) & 1u)) >> 16;   // RNE
    return (u16)r;
}
__device__ __forceinline__ float bf2f(u16 h) {
    return __uint_as_float(((unsigned)h) << 16);
}

// ---------------------------------------------------------------- zero fill
__global__ void kzero(float4* p, long n) {
    long i = (long)blockIdx.x * blockDim.x + threadIdx.x;
    long st = (long)gridDim.x * blockDim.x;
    float4 z; z.x = 0.f; z.y = 0.f; z.z = 0.f; z.w = 0.f;
    for (; i < n; i += st) p[i] = z;
}

// ------------------------------------------------- match_input -> xcl hi/lo
__global__ void kmatch(const float* __restrict__ input, const float* __restrict__ w1,
                       const float* __restrict__ b1, const float* __restrict__ a1,
                       u16* __restrict__ xhi, u16* __restrict__ xlo) {
    __shared__ float xl[64 * 96];
    __shared__ float wl[32 * 65];
    int b = blockIdx.x / 96, y = blockIdx.x % 96;
    int tid = threadIdx.x;
    for (int i = tid; i < 64 * 96; i += 256) {
        int ci = i / 96, xx = i % 96;
        xl[i] = input[(((b * 64 + ci) * 96) + y) * 96 + xx];
    }
    for (int i = tid; i < 2048; i += 256) wl[(i >> 6) * 65 + (i & 63)] = w1[i];
    __syncthreads();
    float aa = a1[0];
    for (int o = tid; o < 96 * 32; o += 256) {
        int xx = o >> 5, c = o & 31;
        float acc = b1[c];
        #pragma unroll
        for (int ci = 0; ci < 64; ci++) acc = fmaf(xl[ci * 96 + xx], wl[c * 65 + ci], acc);
        float v = acc >= 0.f ? acc : aa * acc;
        u16 hi = f2bf(v);
        float lo = v - bf2f(hi);
        int idx = ((b * 98 + y + 1) * 98 + (xx + 1)) * 32 + c;
        xhi[idx] = hi; xlo[idx] = f2bf(lo);
    }
}

// --------------------- small -> ef32 (embed, f32) + rkl hi/lo-interleaved (ref)
__global__ void ksmall(const float* __restrict__ small, const float* __restrict__ wasm,
                       const float* __restrict__ basm, const float* __restrict__ aasm,
                       const float* __restrict__ wm2, const float* __restrict__ bm2,
                       const float* __restrict__ am2,
                       float* __restrict__ ef32, u16* __restrict__ rkl) {
    __shared__ float sl[64 * 48];
    __shared__ float wa[64 * 65];
    __shared__ float wm[32 * 65];
    int b = blockIdx.x / 48, y = blockIdx.x % 48;
    int tid = threadIdx.x;
    for (int i = tid; i < 64 * 48; i += 256) {
        int ci = i / 48, xx = i % 48;
        sl[i] = small[(((b * 64 + ci) * 48) + y) * 48 + xx];
    }
    for (int i = tid; i < 4096; i += 256) wa[(i >> 6) * 65 + (i & 63)] = wasm[i];
    for (int i = tid; i < 2048; i += 256) wm[(i >> 6) * 65 + (i & 63)] = wm2[i];
    __syncthreads();
    float ae = aasm[0], ar = am2[0];
    for (int o = tid; o < 48 * 64; o += 256) {            // embed_w
        int xx = o >> 6, c = o & 63;
        float acc = basm[c];
        #pragma unroll
        for (int ci = 0; ci < 64; ci++) acc = fmaf(sl[ci * 48 + xx], wa[c * 65 + ci], acc);
        float v = acc >= 0.f ? acc : ae * acc;
        ef32[((b * 50 + y + 1) * 50 + (xx + 1)) * 64 + c] = v;
    }
    for (int o = tid; o < 48 * 32; o += 256) {            // ref -> rkl
        int xx = o >> 5, c = o & 31;
        float acc = bm2[c];
        #pragma unroll
        for (int ci = 0; ci < 64; ci++) acc = fmaf(sl[ci * 48 + xx], wm[c * 65 + ci], acc);
        float v = acc >= 0.f ? acc : ar * acc;
        u16 hi = f2bf(v);
        float lo = v - bf2f(hi);
        // rkl[b][row][hl][px][c], row=y+1, px=xx+1
        int base = (((b * 50 + y + 1) * 2) * 50 + (xx + 1)) * 32 + c;
        rkl[base] = hi; rkl[base + 1600] = f2bf(lo);
    }
}

// ------------------------------------------------------------ invnorm per key
__global__ void kinvnorm(const u16* __restrict__ rkl, float* __restrict__ invn) {
    int idx = blockIdx.x * 256 + threadIdx.x;   // 9216 exact
    int b = idx / 2304, l = idx % 2304;
    int ly = l / 48, lx = l % 48;
    float s = 0.f;
    for (int ty = 0; ty < 3; ty++)
        for (int tx = 0; tx < 3; tx++) {
            int base = (((b * 50 + ly + ty) * 2) * 50 + (lx + tx)) * 32;
            #pragma unroll
            for (int c = 0; c < 32; c++) {
                float v = bf2f(rkl[base + c]) + bf2f(rkl[base + 1600 + c]);
                s = fmaf(v, v, s);
            }
        }
    invn[idx] = 10.f / fmaxf(sqrtf(s), 1e-4f);   // SCALE folded in
}

// ------------------------------------------------------------- pack V^T bf16
__global__ void kvtp(const float* __restrict__ ef32, u16* __restrict__ vtp) {
    const int N = 4 * 576 * 2304;
    int st = gridDim.x * blockDim.x;
    for (int i = blockIdx.x * blockDim.x + threadIdx.x; i < N; i += st) {
        int b = i / (576 * 2304);
        int rem = i % (576 * 2304);
        int n = rem / 2304, l = rem % 2304;
        int t = n >> 6, c = n & 63;
        int ly = l / 48 + t / 3, lx = l % 48 + t % 3;
        vtp[i] = f2bf(ef32[((b * 50 + ly) * 50 + lx) * 64 + c]);
    }
}

// ------------------------------------------------------------- fused flash
// grid = 576 (XCD-swizzled); block = 256 (4 waves).
// BM=64 queries (16 px x 4 py), BN=96 keys (2 key rows / iter, 24 iters).
// Score phase: wave (mh,nh) owns 2 py-rows x 48 keys; Q and K-slab in LDS
// (A-frag reuse 2x over mt, B-frag reuse 2x over mt + hi/lo sharing).
// Softmax stats merged across the 2 nh-waves via LDS each iteration.
// PV phase: each wave owns all 64 M x 144 V-cols; P through LDS (stride 104).
template<bool USE_Z>
__launch_bounds__(256, 2)
__global__ void kflash(const u16* __restrict__ xhi, const u16* __restrict__ xlo,
                       const u16* __restrict__ rkl, const u16* __restrict__ vtp,
                       const float* __restrict__ invn, float* __restrict__ zout) {
    __shared__ u16 Qs[2 * 6 * 18 * 32];      // 13824 B  [hl][row][px][c]
    __shared__ u16 Ks[4 * 2 * 50 * 32];      // 25600 B  [row][hl][px][c]
    __shared__ u16 Pl[64 * 104];             // 13312 B
    __shared__ float pmaxl[2][64];
    __shared__ float psuml[2][64];
    __shared__ float alds[64];
    __shared__ float llds[64];               // total ~54.3 KB -> 2 blocks/CU

    int tid = threadIdx.x;
    int w = tid >> 6, lane = tid & 63, l15 = lane & 15, quad = lane >> 4;
    int mh = w & 1, nh = w >> 1;
    // XCD swizzle: XCD = blockIdx % 8 (heuristic); 2 XCDs per sample.
    int bi = blockIdx.x;
    int b = (bi & 7) >> 1;
    int t = ((bi >> 3) << 1) | (bi & 1);     // 0..143
    int px0 = (t % 6) * 16, py0 = (t / 6) * 4;

    const u16* xh = xhi + (size_t)b * 98 * 98 * 32;
    const u16* xl = xlo + (size_t)b * 98 * 98 * 32;
    const u16* rb = rkl + (size_t)b * 160000;
    const float* invb = invn + b * 2304;
    const u16* vbase = vtp + (size_t)b * 576 * 2304 + (size_t)(w * 144 + l15) * 2304 + quad * 8;

    // ---- stage Q (once): rows py0..py0+5, cols px0..px0+17, 32c, hi+lo
    for (int id = tid; id < 864; id += 256) {
        int arr = id >= 432;
        int r2 = arr ? id - 432 : id;
        int row = r2 / 72, c8 = (r2 % 72) * 8;
        const u16* src = (arr ? xl : xh) + (((py0 + row) * 98 + px0) * 32 + c8);
        *(short8*)&Qs[arr * 3456 + row * 576 + c8] = *(const short8*)src;
    }
    // ---- stage K slab for iter 0: global rows 0..3
    for (int id = tid; id < 1600; id += 256)
        *(short8*)&Ks[id * 8] = *(const short8*)(rb + id * 8);

    f32x4 acc[36];
    #pragma unroll
    for (int i = 0; i < 36; i++) acc[i] = (f32x4)0.f;
    float m_run[2][4], l_run[2][4];
    #pragma unroll
    for (int mt = 0; mt < 2; mt++)
        #pragma unroll
        for (int r = 0; r < 4; r++) { m_run[mt][r] = -1e30f; l_run[mt][r] = 0.f; }

    __syncthreads();

    for (int it = 0; it < 24; ++it) {
        int ly0 = it * 2;
        // ---- score: this wave's S[2 py-rows x 16 px, 48 keys]
        f32x4 sf[6];
        #pragma unroll
        for (int i = 0; i < 6; i++) sf[i] = (f32x4)0.f;
        #pragma unroll
        for (int ty = 0; ty < 3; ++ty)
            #pragma unroll
            for (int tx = 0; tx < 3; ++tx) {
                short8 ahi[2], alo[2];
                #pragma unroll
                for (int mt = 0; mt < 2; ++mt) {
                    int qe = ((2 * mh + mt + ty) * 18 + (l15 + tx)) * 32 + quad * 8;
                    ahi[mt] = *(const short8*)&Qs[qe];
                    alo[mt] = *(const short8*)&Qs[3456 + qe];
                }
                #pragma unroll
                for (int lxo = 0; lxo < 3; ++lxo) {
                    int ke = ((nh + ty) * 2) * 1600 + (lxo * 16 + l15 + tx) * 32 + quad * 8;
                    short8 bhi = *(const short8*)&Ks[ke];
                    short8 blo = *(const short8*)&Ks[ke + 1600];
                    #pragma unroll
                    for (int mt = 0; mt < 2; ++mt) {
                        f32x4 s = sf[mt * 3 + lxo];
                        s = __builtin_amdgcn_mfma_f32_16x16x32_bf16(ahi[mt], bhi, s, 0, 0, 0);
                        s = __builtin_amdgcn_mfma_f32_16x16x32_bf16(ahi[mt], blo, s, 0, 0, 0);
                        s = __builtin_amdgcn_mfma_f32_16x16x32_bf16(alo[mt], bhi, s, 0, 0, 0);
                        sf[mt * 3 + lxo] = s;
                    }
                }
            }
        // ---- partial softmax stats over this wave's 48 keys
        float invs[3];
        #pragma unroll
        for (int lxo = 0; lxo < 3; ++lxo)
            invs[lxo] = invb[ly0 * 48 + nh * 48 + lxo * 16 + l15];
        float pm[2][4], ps[2][4];
        #pragma unroll
        for (int mt = 0; mt < 2; ++mt)
            #pragma unroll
            for (int r = 0; r < 4; ++r) {
                float mx = -1e30f;
                #pragma unroll
                for (int lxo = 0; lxo < 3; ++lxo) {
                    float v = sf[mt * 3 + lxo][r] * invs[lxo];
                    sf[mt * 3 + lxo][r] = v;
                    mx = fmaxf(mx, v);
                }
                mx = fmaxf(mx, __shfl_xor(mx, 1));
                mx = fmaxf(mx, __shfl_xor(mx, 2));
                mx = fmaxf(mx, __shfl_xor(mx, 4));
                mx = fmaxf(mx, __shfl_xor(mx, 8));
                pm[mt][r] = mx;
                float s = 0.f;
                #pragma unroll
                for (int lxo = 0; lxo < 3; ++lxo) {
                    float p = __expf(sf[mt * 3 + lxo][r] - mx);
                    sf[mt * 3 + lxo][r] = p;
                    s += p;
                }
                s += __shfl_xor(s, 1);
                s += __shfl_xor(s, 2);
                s += __shfl_xor(s, 4);
                s += __shfl_xor(s, 8);
                ps[mt][r] = s;
            }
        if (l15 == 0) {
            #pragma unroll
            for (int mt = 0; mt < 2; ++mt)
                #pragma unroll
                for (int r = 0; r < 4; ++r) {
                    int gm = (2 * mh + mt) * 16 + quad * 4 + r;
                    pmaxl[nh][gm] = pm[mt][r];
                    psuml[nh][gm] = ps[mt][r];
                }
        }
        __syncthreads();
        // ---- merge halves + running update
        float fsc[2][4];
        #pragma unroll
        for (int mt = 0; mt < 2; ++mt)
            #pragma unroll
            for (int r = 0; r < 4; ++r) {
                int gm = (2 * mh + mt) * 16 + quad * 4 + r;
                float om = pmaxl[1 - nh][gm], os = psuml[1 - nh][gm];
                float imax = fmaxf(pm[mt][r], om);
                float isum = ps[mt][r] * __expf(pm[mt][r] - imax) + os * __expf(om - imax);
                float mnew = fmaxf(m_run[mt][r], imax);
                float alpha = __expf(m_run[mt][r] - mnew);
                l_run[mt][r] = l_run[mt][r] * alpha + isum * __expf(imax - mnew);
                m_run[mt][r] = mnew;
                fsc[mt][r] = __expf(pm[mt][r] - mnew);
                if (l15 == 0 && nh == 0) alds[gm] = alpha;
            }
        // ---- write P (bf16, rescaled to merged max)
        #pragma unroll
        for (int mt = 0; mt < 2; ++mt)
            #pragma unroll
            for (int lxo = 0; lxo < 3; ++lxo)
                #pragma unroll
                for (int r = 0; r < 4; ++r)
                    Pl[((2 * mh + mt) * 16 + quad * 4 + r) * 104 + nh * 48 + lxo * 16 + l15] =
                        f2bf(sf[mt * 3 + lxo][r] * fsc[mt][r]);
        __syncthreads();

        // ---- rescale O by alpha
        float ar_[4][4];
        bool need = false;
        #pragma unroll
        for (int mt2 = 0; mt2 < 4; ++mt2)
            #pragma unroll
            for (int r = 0; r < 4; ++r) {
                ar_[mt2][r] = alds[mt2 * 16 + quad * 4 + r];
                need |= (ar_[mt2][r] != 1.0f);
            }
        if (__any(need)) {
            #pragma unroll
            for (int mt2 = 0; mt2 < 4; ++mt2)
                #pragma unroll
                for (int nt = 0; nt < 9; ++nt)
                    #pragma unroll
                    for (int r = 0; r < 4; ++r) acc[mt2 * 9 + nt][r] *= ar_[mt2][r];
        }
        // ---- PV: O[64, this wave's 144 cols] += P[64,96] @ V[96,144]
        const u16* vb = vbase + ly0 * 48;
        #pragma unroll
        for (int ks = 0; ks < 3; ++ks) {
            short8 pa[4];
            #pragma unroll
            for (int mt2 = 0; mt2 < 4; ++mt2)
                pa[mt2] = *(const short8*)&Pl[(mt2 * 16 + l15) * 104 + ks * 32 + quad * 8];
            #pragma unroll
            for (int nt = 0; nt < 9; ++nt) {
                short8 vv = *(const short8*)(vb + nt * 16 * 2304 + ks * 32);
                #pragma unroll
                for (int mt2 = 0; mt2 < 4; ++mt2)
                    acc[mt2 * 9 + nt] = __builtin_amdgcn_mfma_f32_16x16x32_bf16(pa[mt2], vv, acc[mt2 * 9 + nt], 0, 0, 0);
            }
        }
        // ---- stage next K slab (safe: all waves past score-phase barrier)
        if (it < 23) {
            const u16* src = rb + (ly0 + 2) * 3200;
            for (int id = tid; id < 1600; id += 256)
                *(short8*)&Ks[id * 8] = *(const short8*)(src + id * 8);
        }
        __syncthreads();
    }

    // ---- epilogue
    if (nh == 0 && l15 == 0) {
        #pragma unroll
        for (int mt = 0; mt < 2; ++mt)
            #pragma unroll
            for (int r = 0; r < 4; ++r)
                llds[(2 * mh + mt) * 16 + quad * 4 + r] = l_run[mt][r];
    }
    __syncthreads();
    float rli[4][4];
    #pragma unroll
    for (int mt2 = 0; mt2 < 4; ++mt2)
        #pragma unroll
        for (int r = 0; r < 4; ++r)
            rli[mt2][r] = 1.0f / (llds[mt2 * 16 + quad * 4 + r] * 6.0f);

    if (USE_Z) {
        float* Zb = zout + (size_t)b * 9216 * 576;
        #pragma unroll
        for (int mt2 = 0; mt2 < 4; ++mt2)
            #pragma unroll
            for (int nt = 0; nt < 9; ++nt) {
                int n = w * 144 + nt * 16 + l15;
                #pragma unroll
                for (int r = 0; r < 4; ++r) {
                    int q = (py0 + mt2) * 96 + px0 + quad * 4 + r;
                    Zb[(size_t)q * 576 + n] = acc[mt2 * 9 + nt][r] * rli[mt2][r];
                }
            }
    } else {
        float* ob = zout + (size_t)b * 64 * 191 * 191;
        #pragma unroll
        for (int nt = 0; nt < 9; ++nt) {
            int n = w * 144 + nt * 16 + l15;
            int tt = n >> 6, c = n & 63;
            int ty = tt / 3, tx = tt % 3;
            float* oc = ob + c * (191 * 191);
            #pragma unroll
            for (int mt2 = 0; mt2 < 4; ++mt2) {
                int oy = 2 * (py0 + mt2) + ty - 1;
                #pragma unroll
                for (int r = 0; r < 4; ++r) {
                    int ox = 2 * (px0 + quad * 4 + r) + tx - 1;
                    if ((unsigned)oy < 191u && (unsigned)ox < 191u)
                        atomicAdd(&oc[oy * 191 + ox], acc[mt2 * 9 + nt][r] * rli[mt2][r]);
                }
            }
        }
    }
}

// ------------------------------------------------------------- gather (Z -> out)
// block = (b, q=py-pair-base, 16-ox tile); computes oy=2q and 2q+1.
// Parity stencil: even oy -> ty=1 (py=q); odd oy -> ty=0 (py=q+1), ty=2 (py=q).
// zb padded stride 580 (576%32==0 would give 9-way bank conflicts).
__global__ void kgather(const float* __restrict__ Z, float* __restrict__ out) {
    __shared__ float zb[2 * 9 * 580];   // 41760 B
    int bi = blockIdx.x;                // 4*96*12
    int b = bi / (96 * 12);
    int rem = bi % (96 * 12);
    int q = rem / 12, xt = rem % 12;
    int ox0 = xt * 16, p0 = ox0 >> 1;
    const float* Zb = Z + (size_t)b * 9216 * 576;
    int tid = threadIdx.x;
    for (int id = tid; id < 2592; id += 256) {
        int pi = id / 1296, r2 = id % 1296;
        int pxi = r2 / 144, n4 = r2 % 144;
        int py = q + pi; if (py > 95) py = 95;
        int px = p0 + pxi; if (px > 95) px = 95;
        *(float4*)&zb[(pi * 9 + pxi) * 580 + n4 * 4] =
            *(const float4*)&Zb[(size_t)(py * 96 + px) * 576 + n4 * 4];
    }
    __syncthreads();
    int xi = tid & 15, cq = tid >> 4;
    int ox = ox0 + xi;
    bool oxv = ox <= 190;
    int ntx, txl[2], pxl[2];
    if (xi & 1) { ntx = 2; txl[0] = 0; pxl[0] = (xi + 1) >> 1; txl[1] = 2; pxl[1] = (xi - 1) >> 1; }
    else        { ntx = 1; txl[0] = 1; pxl[0] = xi >> 1; txl[1] = 1; pxl[1] = xi >> 1; }
    int oy0 = 2 * q;
    #pragma unroll
    for (int ck = 0; ck < 4; ++ck) {
        int c = cq + ck * 16;
        float v0 = 0.f, v1 = 0.f;
        for (int j = 0; j < ntx; ++j) {
            int tx = txl[j], pxi = pxl[j];
            // even row: ty=1, pi=0
            v0 += zb[(0 * 9 + pxi) * 580 + (3 + tx) * 64 + c];
            // odd row: ty=0 -> pi=1 ; ty=2 -> pi=0
            v1 += zb[(1 * 9 + pxi) * 580 + (0 + tx) * 64 + c];
            v1 += zb[(0 * 9 + pxi) * 580 + (6 + tx) * 64 + c];
        }
        if (oxv) {
            float* o = out + (((size_t)(b * 64 + c) * 191 + oy0) * 191 + ox);
            *o = v0;
            if (q < 95) *(o + 191) = v1;
        }
    }
}

// --------------------------------------------------------------------- host
extern "C" void kernel_launch(void* const* d_in, const int* in_sizes, int n_in,
                              void* d_out, int out_size, void* d_ws, size_t ws_size,
                              hipStream_t stream) {
    const float* input = (const float*)d_in[0];
    const float* small = (const float*)d_in[1];
    const float* w1 = (const float*)d_in[2];
    const float* b1 = (const float*)d_in[3];
    const float* a1 = (const float*)d_in[4];
    const float* w2 = (const float*)d_in[5];
    const float* b2 = (const float*)d_in[6];
    const float* a2 = (const float*)d_in[7];
    const float* wa = (const float*)d_in[8];
    const float* ba = (const float*)d_in[9];
    const float* aa = (const float*)d_in[10];

    char* ws = (char*)d_ws;
    u16* xhi = (u16*)(ws + 0);              //  2,458,624
    u16* xlo = (u16*)(ws + 2458624);        //  2,458,624
    u16* rkl = (u16*)(ws + 4917248);        //  2,560,000
    float* ef = (float*)(ws + 7477248);     //  2,560,000
    u16* vtp = (u16*)(ws + 10037248);       // 10,616,832
    float* invn = (float*)(ws + 20654080);  //     36,864
    float* Zbuf = (float*)(ws + 20690944);  // 84,934,656 -> total 105,625,600
    float* out = (float*)d_out;

    bool useZ = (ws_size >= (size_t)105625600);

    // zero halo'd staging region (xhi,xlo,rkl,ef); vtp/invn/Z fully written
    kzero<<<1024, 256, 0, stream>>>((float4*)ws, 10037248 / 16);
    if (!useZ)
        kzero<<<1024, 256, 0, stream>>>((float4*)out, 37356544 / 16);
    kmatch<<<384, 256, 0, stream>>>(input, w1, b1, a1, xhi, xlo);
    ksmall<<<192, 256, 0, stream>>>(small, wa, ba, aa, w2, b2, a2, ef, rkl);
    kinvnorm<<<36, 256, 0, stream>>>(rkl, invn);
    kvtp<<<2048, 256, 0, stream>>>(ef, vtp);
    if (useZ) {
        kflash<true><<<576, 256, 0, stream>>>(xhi, xlo, rkl, vtp, invn, Zbuf);
        kgather<<<4608, 256, 0, stream>>>(Zbuf, out);
    } else {
        kflash<false><<<576, 256, 0, stream>>>(xhi, xlo, rkl, vtp, invn, out);
    }
}

// Round 3
// 840.079 us; speedup vs baseline: 2.4795x; 1.2376x over previous
//
#include <hip/hip_runtime.h>

// CrossScaleAttention on MI355X — round 3.
// R2 post-mortem: fused flash kernel was barrier/latency-bound (MfmaUtil 11.6%,
// all pipes <15%, 3 barriers/iter, cross-wave softmax merge, 2 blocks/CU).
// R3: drop the softmax max-shift entirely (logits |s| <~ 70 << 88 = fp32 exp
// overflow; Z = PV/l invariant to the shift), materialize P to workspace, and
// split into barrier-light GEMM-shaped kernels:
//   kscoreP: S = (Q.K)·invs hi/lo GEMM -> p=exp(s) -> P (bf16, HBM/L3) + l (atomics)
//   kpv:     Z = P·V^T / (6l)   (clean GEMM, dbuf LDS P slabs, 1 barrier/iter)
//   kgather: stride-2 overlap-add Z -> out (unchanged from R2)
//
// Workspace (full path, 275,642,368 B):
//   xhi/xlo : [4][98][98][32] bf16 match_input hi/lo, zero halo
//   rkl     : [4][50][2][50][32] bf16 ref, hi/lo interleaved per row, zero halo
//   ef32    : [4][50][50][64] f32 embed_w, zero halo
//   vtp     : [4][576][2304] bf16 V^T (n = tap*64+c, l = ly*48+lx)
//   invn    : [4][2304] f32 10/max(norm,1e-4)
//   lsum    : [nb][9216] f32 softmax denominators (atomic-accumulated)
//   P       : [nb][9216][2304] bf16 exp(scores)
//   Z       : [nb][9216][576] f32
// Fallback (ws < 276 MB): loop b0 over samples with nb=1 (84.4 MB).

typedef unsigned short u16;
typedef __attribute__((ext_vector_type(8))) short short8;   // 8 bf16 = 4 VGPR
typedef __attribute__((ext_vector_type(4))) float f32x4;

__device__ __forceinline__ u16 f2bf(float f) {
    unsigned u = __float_as_uint(f);
    unsigned r = (u + 0x7FFFu + ((u >> 16) & 1u)) >> 16;   // RNE
    return (u16)r;
}
__device__ __forceinline__ float bf2f(u16 h) {
    return __uint_as_float(((unsigned)h) << 16);
}

// ---------------------------------------------------------------- zero fill
__global__ void kzero(float4* p, long n) {
    long i = (long)blockIdx.x * blockDim.x + threadIdx.x;
    long st = (long)gridDim.x * blockDim.x;
    float4 z; z.x = 0.f; z.y = 0.f; z.z = 0.f; z.w = 0.f;
    for (; i < n; i += st) p[i] = z;
}

// ------------------------------------------------- match_input -> xcl hi/lo
__global__ void kmatch(const float* __restrict__ input, const float* __restrict__ w1,
                       const float* __restrict__ b1, const float* __restrict__ a1,
                       u16* __restrict__ xhi, u16* __restrict__ xlo) {
    __shared__ float xl[64 * 96];
    __shared__ float wl[32 * 65];
    int b = blockIdx.x / 96, y = blockIdx.x % 96;
    int tid = threadIdx.x;
    for (int i = tid; i < 64 * 96; i += 256) {
        int ci = i / 96, xx = i % 96;
        xl[i] = input[(((b * 64 + ci) * 96) + y) * 96 + xx];
    }
    for (int i = tid; i < 2048; i += 256) wl[(i >> 6) * 65 + (i & 63)] = w1[i];
    __syncthreads();
    float aa = a1[0];
    for (int o = tid; o < 96 * 32; o += 256) {
        int xx = o >> 5, c = o & 31;
        float acc = b1[c];
        #pragma unroll
        for (int ci = 0; ci < 64; ci++) acc = fmaf(xl[ci * 96 + xx], wl[c * 65 + ci], acc);
        float v = acc >= 0.f ? acc : aa * acc;
        u16 hi = f2bf(v);
        float lo = v - bf2f(hi);
        int idx = ((b * 98 + y + 1) * 98 + (xx + 1)) * 32 + c;
        xhi[idx] = hi; xlo[idx] = f2bf(lo);
    }
}

// --------------------- small -> ef32 (embed, f32) + rkl hi/lo-interleaved (ref)
__global__ void ksmall(const float* __restrict__ small, const float* __restrict__ wasm,
                       const float* __restrict__ basm, const float* __restrict__ aasm,
                       const float* __restrict__ wm2, const float* __restrict__ bm2,
                       const float* __restrict__ am2,
                       float* __restrict__ ef32, u16* __restrict__ rkl) {
    __shared__ float sl[64 * 48];
    __shared__ float wa[64 * 65];
    __shared__ float wm[32 * 65];
    int b = blockIdx.x / 48, y = blockIdx.x % 48;
    int tid = threadIdx.x;
    for (int i = tid; i < 64 * 48; i += 256) {
        int ci = i / 48, xx = i % 48;
        sl[i] = small[(((b * 64 + ci) * 48) + y) * 48 + xx];
    }
    for (int i = tid; i < 4096; i += 256) wa[(i >> 6) * 65 + (i & 63)] = wasm[i];
    for (int i = tid; i < 2048; i += 256) wm[(i >> 6) * 65 + (i & 63)] = wm2[i];
    __syncthreads();
    float ae = aasm[0], ar = am2[0];
    for (int o = tid; o < 48 * 64; o += 256) {            // embed_w
        int xx = o >> 6, c = o & 63;
        float acc = basm[c];
        #pragma unroll
        for (int ci = 0; ci < 64; ci++) acc = fmaf(sl[ci * 48 + xx], wa[c * 65 + ci], acc);
        float v = acc >= 0.f ? acc : ae * acc;
        ef32[((b * 50 + y + 1) * 50 + (xx + 1)) * 64 + c] = v;
    }
    for (int o = tid; o < 48 * 32; o += 256) {            // ref -> rkl
        int xx = o >> 5, c = o & 31;
        float acc = bm2[c];
        #pragma unroll
        for (int ci = 0; ci < 64; ci++) acc = fmaf(sl[ci * 48 + xx], wm[c * 65 + ci], acc);
        float v = acc >= 0.f ? acc : ar * acc;
        u16 hi = f2bf(v);
        float lo = v - bf2f(hi);
        int base = (((b * 50 + y + 1) * 2) * 50 + (xx + 1)) * 32 + c;
        rkl[base] = hi; rkl[base + 1600] = f2bf(lo);
    }
}

// ------------------------------------------------------------ invnorm per key
__global__ void kinvnorm(const u16* __restrict__ rkl, float* __restrict__ invn) {
    int idx = blockIdx.x * 256 + threadIdx.x;   // 9216 exact
    int b = idx / 2304, l = idx % 2304;
    int ly = l / 48, lx = l % 48;
    float s = 0.f;
    for (int ty = 0; ty < 3; ty++)
        for (int tx = 0; tx < 3; tx++) {
            int base = (((b * 50 + ly + ty) * 2) * 50 + (lx + tx)) * 32;
            #pragma unroll
            for (int c = 0; c < 32; c++) {
                float v = bf2f(rkl[base + c]) + bf2f(rkl[base + 1600 + c]);
                s = fmaf(v, v, s);
            }
        }
    invn[idx] = 10.f / fmaxf(sqrtf(s), 1e-4f);   // SCALE folded in
}

// ------------------------------------------------------------- pack V^T bf16
__global__ void kvtp(const float* __restrict__ ef32, u16* __restrict__ vtp) {
    const int N = 4 * 576 * 2304;
    int st = gridDim.x * blockDim.x;
    for (int i = blockIdx.x * blockDim.x + threadIdx.x; i < N; i += st) {
        int b = i / (576 * 2304);
        int rem = i % (576 * 2304);
        int n = rem / 2304, l = rem % 2304;
        int t = n >> 6, c = n & 63;
        int ly = l / 48 + t / 3, lx = l % 48 + t % 3;
        vtp[i] = f2bf(ef32[((b * 50 + ly) * 50 + lx) * 64 + c]);
    }
}

// ------------------------------------------------------------- score + P + l
// grid = nb*144*4: (brel, q-tile of 64, key-slab g of 576 keys).
// 6 iters x 96 keys (2 key rows). Wave (mh,nh): 2 M-tiles x (key row ly0+nh).
// No softmax shift: p = exp(s*invs) directly. l accumulated in regs across
// iters, one atomicAdd per row per wave at the end. Barriers: 2/iter (staging).
__launch_bounds__(256, 4)
__global__ void kscoreP(const u16* __restrict__ xhi, const u16* __restrict__ xlo,
                        const u16* __restrict__ rkl, const float* __restrict__ invn,
                        u16* __restrict__ P, float* __restrict__ lsum, int b0) {
    __shared__ u16 Qs[2 * 6 * 18 * 32];      // 13824 B  [hl][row][px][c]
    __shared__ u16 Ks[4 * 3200];             // 25600 B  4 rows x [hl][px][c]

    int tid = threadIdx.x;
    int w = tid >> 6, lane = tid & 63, l15 = lane & 15, quad = lane >> 4;
    int mh = w & 1, nh = w >> 1;
    int bi = blockIdx.x;
    int g = bi & 3;
    int rest = bi >> 2;
    int brel = rest / 144, t = rest % 144;
    int b = b0 + brel;
    int px0 = (t % 6) * 16, py0 = (t / 6) * 4;

    const u16* xh = xhi + (size_t)b * 98 * 98 * 32;
    const u16* xl = xlo + (size_t)b * 98 * 98 * 32;
    const u16* rb = rkl + (size_t)b * 160000;
    const float* invb = invn + b * 2304;
    u16* Pb = P + (size_t)brel * 9216 * 2304;
    float* lb = lsum + brel * 9216;

    // stage Q (once): rows py0-1..py0+4 (halo coords), cols px0-1..px0+16, hi+lo
    for (int id = tid; id < 864; id += 256) {
        int arr = id >= 432;
        int r2 = arr ? id - 432 : id;
        int row = r2 / 72, c8 = (r2 % 72) * 8;
        const u16* src = (arr ? xl : xh) + (((py0 + row) * 98 + px0) * 32 + c8);
        *(short8*)&Qs[arr * 3456 + row * 576 + c8] = *(const short8*)src;
    }

    float lacc[2][4] = {{0.f, 0.f, 0.f, 0.f}, {0.f, 0.f, 0.f, 0.f}};

    for (int it = 0; it < 6; ++it) {
        int ly0 = g * 12 + it * 2;
        __syncthreads();   // Qs ready (it 0) / previous iter done reading Ks
        for (int id = tid; id < 1600; id += 256)
            *(short8*)&Ks[id * 8] = *(const short8*)(rb + ly0 * 3200 + id * 8);
        __syncthreads();

        f32x4 sf[6];
        #pragma unroll
        for (int i = 0; i < 6; i++) sf[i] = (f32x4)0.f;
        #pragma unroll
        for (int ty = 0; ty < 3; ++ty)
            #pragma unroll
            for (int tx = 0; tx < 3; ++tx) {
                short8 ahi[2], alo[2];
                #pragma unroll
                for (int mt = 0; mt < 2; ++mt) {
                    int qe = ((2 * mh + mt + ty) * 18 + (l15 + tx)) * 32 + quad * 8;
                    ahi[mt] = *(const short8*)&Qs[qe];
                    alo[mt] = *(const short8*)&Qs[3456 + qe];
                }
                #pragma unroll
                for (int lxo = 0; lxo < 3; ++lxo) {
                    int ke = (nh + ty) * 3200 + (lxo * 16 + l15 + tx) * 32 + quad * 8;
                    short8 bhi = *(const short8*)&Ks[ke];
                    short8 blo = *(const short8*)&Ks[ke + 1600];
                    #pragma unroll
                    for (int mt = 0; mt < 2; ++mt) {
                        f32x4 s = sf[mt * 3 + lxo];
                        s = __builtin_amdgcn_mfma_f32_16x16x32_bf16(ahi[mt], bhi, s, 0, 0, 0);
                        s = __builtin_amdgcn_mfma_f32_16x16x32_bf16(ahi[mt], blo, s, 0, 0, 0);
                        s = __builtin_amdgcn_mfma_f32_16x16x32_bf16(alo[mt], bhi, s, 0, 0, 0);
                        sf[mt * 3 + lxo] = s;
                    }
                }
            }

        float invs[3];
        #pragma unroll
        for (int lxo = 0; lxo < 3; ++lxo)
            invs[lxo] = invb[(ly0 + nh) * 48 + lxo * 16 + l15];

        #pragma unroll
        for (int mt = 0; mt < 2; ++mt)
            #pragma unroll
            for (int r = 0; r < 4; ++r) {
                int q = (py0 + 2 * mh + mt) * 96 + px0 + quad * 4 + r;
                u16* prow = Pb + (size_t)q * 2304 + (ly0 + nh) * 48 + l15;
                float s = 0.f;
                #pragma unroll
                for (int lxo = 0; lxo < 3; ++lxo) {
                    float p = __expf(sf[mt * 3 + lxo][r] * invs[lxo]);
                    u16 h = f2bf(p);
                    prow[lxo * 16] = h;
                    s += bf2f(h);      // l from bf16-rounded p (match P exactly)
                }
                lacc[mt][r] += s;
            }
    }

    // final l reduction: sum over l15 within each 16-lane group, one atomic/row
    #pragma unroll
    for (int mt = 0; mt < 2; ++mt)
        #pragma unroll
        for (int r = 0; r < 4; ++r) {
            float v = lacc[mt][r];
            v += __shfl_xor(v, 1);
            v += __shfl_xor(v, 2);
            v += __shfl_xor(v, 4);
            v += __shfl_xor(v, 8);
            if (l15 == 0)
                atomicAdd(&lb[(py0 + 2 * mh + mt) * 96 + px0 + quad * 4 + r], v);
        }
}

// ------------------------------------------------------------- PV GEMM
// grid = nb*144: (brel, q-tile of 64). Block = 4 waves; wave w owns all 64 M
// rows x 144 V-cols (n = w*144 + nt*16 + l15). K = 2304 in 24 slabs of 96.
// P slab (64x96 bf16) double-buffered in LDS in MFMA-fragment-tiled layout
// (A-frag reads are contiguous 1024 B/wave -> conflict-free); global loads
// register-prefetched one iter ahead. 1 barrier/iter.
__launch_bounds__(256, 2)
__global__ void kpv(const u16* __restrict__ P, const u16* __restrict__ vtp,
                    const float* __restrict__ lsum, float* __restrict__ Z, int b0) {
    __shared__ u16 Ps[2][6144];   // [buf][ (mt*3+ks)*512 + l15*32 + quad*8 ]

    int tid = threadIdx.x;
    int w = tid >> 6, lane = tid & 63, l15 = lane & 15, quad = lane >> 4;
    int bi = blockIdx.x;
    int brel = bi / 144, qt = bi % 144;
    int b = b0 + brel;
    int q0 = qt * 64;

    const u16* Pb = P + (size_t)brel * 9216 * 2304 + (size_t)q0 * 2304;
    const u16* vw = vtp + (size_t)b * 576 * 2304 + (size_t)(w * 144 + l15) * 2304 + quad * 8;

    // staging index precompute: 768 short8 per slab, 3 per thread
    int srow[3], skc[3], sdst[3];
    #pragma unroll
    for (int j = 0; j < 3; ++j) {
        int id = tid + j * 256;
        int row = id / 12, kc = id % 12;
        srow[j] = row; skc[j] = kc;
        sdst[j] = ((row >> 4) * 3 + (kc >> 2)) * 512 + (row & 15) * 32 + (kc & 3) * 8;
    }

    f32x4 acc[36];
    #pragma unroll
    for (int i = 0; i < 36; i++) acc[i] = (f32x4)0.f;

    short8 tmp[3];
    #pragma unroll
    for (int j = 0; j < 3; ++j)
        tmp[j] = *(const short8*)(Pb + (size_t)srow[j] * 2304 + skc[j] * 8);
    #pragma unroll
    for (int j = 0; j < 3; ++j) *(short8*)&Ps[0][sdst[j]] = tmp[j];
    __syncthreads();

    for (int it = 0; it < 24; ++it) {
        const u16* pc = Ps[it & 1];
        if (it < 23) {
            #pragma unroll
            for (int j = 0; j < 3; ++j)
                tmp[j] = *(const short8*)(Pb + (size_t)srow[j] * 2304 + (it + 1) * 96 + skc[j] * 8);
        }
        #pragma unroll
        for (int ks = 0; ks < 3; ++ks) {
            short8 pa[4];
            #pragma unroll
            for (int mt = 0; mt < 4; ++mt)
                pa[mt] = *(const short8*)&pc[(mt * 3 + ks) * 512 + l15 * 32 + quad * 8];
            #pragma unroll
            for (int nt = 0; nt < 9; ++nt) {
                short8 vv = *(const short8*)(vw + (size_t)nt * 16 * 2304 + it * 96 + ks * 32);
                #pragma unroll
                for (int mt = 0; mt < 4; ++mt)
                    acc[mt * 9 + nt] = __builtin_amdgcn_mfma_f32_16x16x32_bf16(pa[mt], vv, acc[mt * 9 + nt], 0, 0, 0);
            }
        }
        if (it < 23) {
            #pragma unroll
            for (int j = 0; j < 3; ++j) *(short8*)&Ps[(it + 1) & 1][sdst[j]] = tmp[j];
        }
        __syncthreads();
    }

    // epilogue: /(6l), write Z
    const float* lb = lsum + brel * 9216 + q0;
    float* Zb = Z + (size_t)brel * 9216 * 576 + (size_t)q0 * 576;
    #pragma unroll
    for (int mt = 0; mt < 4; ++mt)
        #pragma unroll
        for (int r = 0; r < 4; ++r) {
            int row = mt * 16 + quad * 4 + r;
            float rl = 1.0f / (lb[row] * 6.0f);
            #pragma unroll
            for (int nt = 0; nt < 9; ++nt)
                Zb[(size_t)row * 576 + w * 144 + nt * 16 + l15] = acc[mt * 9 + nt][r] * rl;
        }
}

// ------------------------------------------------------------- gather (Z -> out)
__global__ void kgather(const float* __restrict__ Z, float* __restrict__ out, int b0) {
    __shared__ float zb[2 * 9 * 580];   // 41760 B
    int bi = blockIdx.x;                // nb*96*12
    int brel = bi / (96 * 12);
    int rem = bi % (96 * 12);
    int b = b0 + brel;
    int q = rem / 12, xt = rem % 12;
    int ox0 = xt * 16, p0 = ox0 >> 1;
    const float* Zb = Z + (size_t)brel * 9216 * 576;
    int tid = threadIdx.x;
    for (int id = tid; id < 2592; id += 256) {
        int pi = id / 1296, r2 = id % 1296;
        int pxi = r2 / 144, n4 = r2 % 144;
        int py = q + pi; if (py > 95) py = 95;
        int px = p0 + pxi; if (px > 95) px = 95;
        *(float4*)&zb[(pi * 9 + pxi) * 580 + n4 * 4] =
            *(const float4*)&Zb[(size_t)(py * 96 + px) * 576 + n4 * 4];
    }
    __syncthreads();
    int xi = tid & 15, cq = tid >> 4;
    int ox = ox0 + xi;
    bool oxv = ox <= 190;
    int ntx, txl[2], pxl[2];
    if (xi & 1) { ntx = 2; txl[0] = 0; pxl[0] = (xi + 1) >> 1; txl[1] = 2; pxl[1] = (xi - 1) >> 1; }
    else        { ntx = 1; txl[0] = 1; pxl[0] = xi >> 1; txl[1] = 1; pxl[1] = xi >> 1; }
    int oy0 = 2 * q;
    #pragma unroll
    for (int ck = 0; ck < 4; ++ck) {
        int c = cq + ck * 16;
        float v0 = 0.f, v1 = 0.f;
        for (int j = 0; j < ntx; ++j) {
            int tx = txl[j], pxi = pxl[j];
            v0 += zb[(0 * 9 + pxi) * 580 + (3 + tx) * 64 + c];
            v1 += zb[(1 * 9 + pxi) * 580 + (0 + tx) * 64 + c];
            v1 += zb[(0 * 9 + pxi) * 580 + (6 + tx) * 64 + c];
        }
        if (oxv) {
            float* o = out + (((size_t)(b * 64 + c) * 191 + oy0) * 191 + ox);
            *o = v0;
            if (q < 95) *(o + 191) = v1;
        }
    }
}

// --------------------------------------------------------------------- host
extern "C" void kernel_launch(void* const* d_in, const int* in_sizes, int n_in,
                              void* d_out, int out_size, void* d_ws, size_t ws_size,
                              hipStream_t stream) {
    const float* input = (const float*)d_in[0];
    const float* small = (const float*)d_in[1];
    const float* w1 = (const float*)d_in[2];
    const float* b1 = (const float*)d_in[3];
    const float* a1 = (const float*)d_in[4];
    const float* w2 = (const float*)d_in[5];
    const float* b2 = (const float*)d_in[6];
    const float* a2 = (const float*)d_in[7];
    const float* wa = (const float*)d_in[8];
    const float* ba = (const float*)d_in[9];
    const float* aa = (const float*)d_in[10];

    char* ws = (char*)d_ws;
    u16* xhi = (u16*)(ws + 0);              //  2,458,624
    u16* xlo = (u16*)(ws + 2458624);        //  2,458,624
    u16* rkl = (u16*)(ws + 4917248);        //  2,560,000
    float* ef = (float*)(ws + 7477248);     //  2,560,000
    u16* vtp = (u16*)(ws + 10037248);       // 10,616,832
    float* invn = (float*)(ws + 20654080);  //     36,864
    const size_t PREP = 20690944;

    // full path: nb=4 -> lsum 147456 + P 169869312 + Z 84934656 = 275,642,368 B
    // fallback : nb=1 -> lsum  36864 + P  42467328 + Z 21233664 =  84,428,800 B
    int nb = (ws_size >= (size_t)275642368) ? 4 : 1;
    float* lsum = (float*)(ws + PREP);
    size_t lsz = (size_t)nb * 9216 * 4;
    u16* P = (u16*)(ws + PREP + lsz);
    size_t psz = (size_t)nb * 9216 * 2304 * 2;
    float* Zbuf = (float*)(ws + PREP + lsz + psz);
    float* out = (float*)d_out;

    // zero halo'd staging region (xhi,xlo,rkl,ef); vtp/invn/P/Z fully written
    kzero<<<1024, 256, 0, stream>>>((float4*)ws, 10037248 / 16);
    kmatch<<<384, 256, 0, stream>>>(input, w1, b1, a1, xhi, xlo);
    ksmall<<<192, 256, 0, stream>>>(small, wa, ba, aa, w2, b2, a2, ef, rkl);
    kinvnorm<<<36, 256, 0, stream>>>(rkl, invn);
    kvtp<<<2048, 256, 0, stream>>>(ef, vtp);

    for (int b0 = 0; b0 < 4; b0 += nb) {
        kzero<<<36, 256, 0, stream>>>((float4*)lsum, (long)nb * 2304);
        kscoreP<<<nb * 576, 256, 0, stream>>>(xhi, xlo, rkl, invn, P, lsum, b0);
        kpv<<<nb * 144, 256, 0, stream>>>(P, vtp, lsum, Zbuf, b0);
        kgather<<<nb * 1152, 256, 0, stream>>>(Zbuf, out, b0);
    }
}

// Round 4
// 793.506 us; speedup vs baseline: 2.6251x; 1.0587x over previous
//
#include <hip/hip_runtime.h>

// CrossScaleAttention on MI355X — round 4.
// R3 post-mortem: kscoreP hit 834 TF, but ws < 276 MB forced nb=1 and kpv
// (144 blocks, 1 wave/SIMD) ran at 194 TF = 504 of 840 µs; P cost 505 MB of
// HBM round-trip. R4: with no softmax max-shift there are no cross-wave
// merges, so fuse score+PV into ONE dispatch over all 4 samples (576 blocks):
// score phase (R3 kscoreP inner, proven 834 TF) -> P into LDS (kpv tiled
// layout, conflict-free) -> PV phase (R3 kpv inner). l stays in registers +
// one LDS merge. 2 barriers/iter, K-slab double-buffered w/ reg prefetch.
//
// Workspace (105,625,600 B — empirically available since R2):
//   xhi/xlo : [4][98][98][32] bf16 match_input hi/lo, zero halo
//   rkl     : [4][50][2][50][32] bf16 ref, hi/lo interleaved, zero halo
//   ef32    : [4][50][50][64] f32 embed_w, zero halo
//   vtp     : [4][576][2304] bf16 V^T (n = tap*64+c, l = ly*48+lx)
//   invn    : [4][2304] f32 10/max(norm,1e-4)
//   Z       : [nb][9216][576] f32
// Fallback (ws < 105.6 MB): per-sample loop (41.9 MB).

typedef unsigned short u16;
typedef __attribute__((ext_vector_type(8))) short short8;   // 8 bf16 = 4 VGPR
typedef __attribute__((ext_vector_type(4))) float f32x4;

__device__ __forceinline__ u16 f2bf(float f) {
    unsigned u = __float_as_uint(f);
    unsigned r = (u + 0x7FFFu + ((u >> 16) & 1u)) >> 16;   // RNE
    return (u16)r;
}
__device__ __forceinline__ float bf2f(u16 h) {
    return __uint_as_float(((unsigned)h) << 16);
}

// ---------------------------------------------------------------- zero fill
__global__ void kzero(float4* p, long n) {
    long i = (long)blockIdx.x * blockDim.x + threadIdx.x;
    long st = (long)gridDim.x * blockDim.x;
    float4 z; z.x = 0.f; z.y = 0.f; z.z = 0.f; z.w = 0.f;
    for (; i < n; i += st) p[i] = z;
}

// ------------------------------------------------- match_input -> xcl hi/lo
__global__ void kmatch(const float* __restrict__ input, const float* __restrict__ w1,
                       const float* __restrict__ b1, const float* __restrict__ a1,
                       u16* __restrict__ xhi, u16* __restrict__ xlo) {
    __shared__ float xl[64 * 96];
    __shared__ float wl[32 * 65];
    int b = blockIdx.x / 96, y = blockIdx.x % 96;
    int tid = threadIdx.x;
    for (int i = tid; i < 64 * 96; i += 256) {
        int ci = i / 96, xx = i % 96;
        xl[i] = input[(((b * 64 + ci) * 96) + y) * 96 + xx];
    }
    for (int i = tid; i < 2048; i += 256) wl[(i >> 6) * 65 + (i & 63)] = w1[i];
    __syncthreads();
    float aa = a1[0];
    for (int o = tid; o < 96 * 32; o += 256) {
        int xx = o >> 5, c = o & 31;
        float acc = b1[c];
        #pragma unroll
        for (int ci = 0; ci < 64; ci++) acc = fmaf(xl[ci * 96 + xx], wl[c * 65 + ci], acc);
        float v = acc >= 0.f ? acc : aa * acc;
        u16 hi = f2bf(v);
        float lo = v - bf2f(hi);
        int idx = ((b * 98 + y + 1) * 98 + (xx + 1)) * 32 + c;
        xhi[idx] = hi; xlo[idx] = f2bf(lo);
    }
}

// --------------------- small -> ef32 (embed, f32) + rkl hi/lo-interleaved (ref)
__global__ void ksmall(const float* __restrict__ small, const float* __restrict__ wasm,
                       const float* __restrict__ basm, const float* __restrict__ aasm,
                       const float* __restrict__ wm2, const float* __restrict__ bm2,
                       const float* __restrict__ am2,
                       float* __restrict__ ef32, u16* __restrict__ rkl) {
    __shared__ float sl[64 * 48];
    __shared__ float wa[64 * 65];
    __shared__ float wm[32 * 65];
    int b = blockIdx.x / 48, y = blockIdx.x % 48;
    int tid = threadIdx.x;
    for (int i = tid; i < 64 * 48; i += 256) {
        int ci = i / 48, xx = i % 48;
        sl[i] = small[(((b * 64 + ci) * 48) + y) * 48 + xx];
    }
    for (int i = tid; i < 4096; i += 256) wa[(i >> 6) * 65 + (i & 63)] = wasm[i];
    for (int i = tid; i < 2048; i += 256) wm[(i >> 6) * 65 + (i & 63)] = wm2[i];
    __syncthreads();
    float ae = aasm[0], ar = am2[0];
    for (int o = tid; o < 48 * 64; o += 256) {            // embed_w
        int xx = o >> 6, c = o & 63;
        float acc = basm[c];
        #pragma unroll
        for (int ci = 0; ci < 64; ci++) acc = fmaf(sl[ci * 48 + xx], wa[c * 65 + ci], acc);
        float v = acc >= 0.f ? acc : ae * acc;
        ef32[((b * 50 + y + 1) * 50 + (xx + 1)) * 64 + c] = v;
    }
    for (int o = tid; o < 48 * 32; o += 256) {            // ref -> rkl
        int xx = o >> 5, c = o & 31;
        float acc = bm2[c];
        #pragma unroll
        for (int ci = 0; ci < 64; ci++) acc = fmaf(sl[ci * 48 + xx], wm[c * 65 + ci], acc);
        float v = acc >= 0.f ? acc : ar * acc;
        u16 hi = f2bf(v);
        float lo = v - bf2f(hi);
        int base = (((b * 50 + y + 1) * 2) * 50 + (xx + 1)) * 32 + c;
        rkl[base] = hi; rkl[base + 1600] = f2bf(lo);
    }
}

// ------------------------------------------------------------ invnorm per key
__global__ void kinvnorm(const u16* __restrict__ rkl, float* __restrict__ invn) {
    int idx = blockIdx.x * 256 + threadIdx.x;   // 9216 exact
    int b = idx / 2304, l = idx % 2304;
    int ly = l / 48, lx = l % 48;
    float s = 0.f;
    for (int ty = 0; ty < 3; ty++)
        for (int tx = 0; tx < 3; tx++) {
            int base = (((b * 50 + ly + ty) * 2) * 50 + (lx + tx)) * 32;
            #pragma unroll
            for (int c = 0; c < 32; c++) {
                float v = bf2f(rkl[base + c]) + bf2f(rkl[base + 1600 + c]);
                s = fmaf(v, v, s);
            }
        }
    invn[idx] = 10.f / fmaxf(sqrtf(s), 1e-4f);   // SCALE folded in
}

// ------------------------------------------------------------- pack V^T bf16
__global__ void kvtp(const float* __restrict__ ef32, u16* __restrict__ vtp) {
    const int N = 4 * 576 * 2304;
    int st = gridDim.x * blockDim.x;
    for (int i = blockIdx.x * blockDim.x + threadIdx.x; i < N; i += st) {
        int b = i / (576 * 2304);
        int rem = i % (576 * 2304);
        int n = rem / 2304, l = rem % 2304;
        int t = n >> 6, c = n & 63;
        int ly = l / 48 + t / 3, lx = l % 48 + t % 3;
        vtp[i] = f2bf(ef32[((b * 50 + ly) * 50 + lx) * 64 + c]);
    }
}

// ------------------------------------------------------------- fused score+PV
__launch_bounds__(256, 2)
__global__ void kfused(const u16* __restrict__ xhi, const u16* __restrict__ xlo,
                       const u16* __restrict__ rkl, const u16* __restrict__ vtp,
                       const float* __restrict__ invn, float* __restrict__ Z,
                       int b0, int nb) {
    __shared__ u16 Qs[2 * 6 * 18 * 32];      // 13824 B  [hl][row][px][c]
    __shared__ u16 Ks[2][4 * 3200];          // 51200 B  dbuf, 4 rows x [hl][px][c]
    __shared__ u16 Pl[12 * 512];             // 12288 B  [(mt*3+kb)*512 + m16*32 + (k&31)]
    __shared__ float llds[2][64];            // 512 B    -> total 77824 B, 2 blk/CU

    int tid = threadIdx.x;
    int w = tid >> 6, lane = tid & 63, l15 = lane & 15, quad = lane >> 4;
    int mh = w & 1, nh = w >> 1;
    int bi = blockIdx.x, brel, t;
    if (nb == 4) { brel = (bi & 7) >> 1; t = ((bi >> 3) << 1) | (bi & 1); }
    else         { brel = 0; t = bi; }
    int b = b0 + brel;
    int px0 = (t % 6) * 16, py0 = (t / 6) * 4;

    const u16* xh = xhi + (size_t)b * 98 * 98 * 32;
    const u16* xl = xlo + (size_t)b * 98 * 98 * 32;
    const u16* rb = rkl + (size_t)b * 160000;
    const float* invb = invn + b * 2304;
    const u16* vw = vtp + (size_t)b * 576 * 2304 + (size_t)(w * 144 + l15) * 2304 + quad * 8;

    // stage Q once: halo rows py0..py0+5, halo cols px0..px0+17, hi+lo
    for (int id = tid; id < 864; id += 256) {
        int arr = id >= 432;
        int r2 = arr ? id - 432 : id;
        int row = r2 / 72, c8 = (r2 % 72) * 8;
        const u16* src = (arr ? xl : xh) + (((py0 + row) * 98 + px0) * 32 + c8);
        *(short8*)&Qs[arr * 3456 + row * 576 + c8] = *(const short8*)src;
    }
    // stage K slab 0 (halo rows 0..3)
    for (int id = tid; id < 1600; id += 256)
        *(short8*)&Ks[0][id * 8] = *(const short8*)(rb + id * 8);

    f32x4 acc[36];
    #pragma unroll
    for (int i = 0; i < 36; i++) acc[i] = (f32x4)0.f;
    float lacc[2][4] = {{0.f, 0.f, 0.f, 0.f}, {0.f, 0.f, 0.f, 0.f}};

    __syncthreads();

    for (int it = 0; it < 24; ++it) {
        int ly0 = it * 2;
        const u16* kc = Ks[it & 1];

        // prefetch next K slab into regs (overlaps score MFMA)
        short8 ktmp[7];
        if (it < 23) {
            const u16* src = rb + (ly0 + 2) * 3200;
            #pragma unroll
            for (int j = 0; j < 6; ++j)
                ktmp[j] = *(const short8*)(src + (tid + j * 256) * 8);
            if (tid < 64) ktmp[6] = *(const short8*)(src + (tid + 1536) * 8);
        }

        // ---- score: S[2 py x 16 px, 48 keys] per wave, hi/lo 3-MFMA split
        f32x4 sf[6];
        #pragma unroll
        for (int i = 0; i < 6; i++) sf[i] = (f32x4)0.f;
        #pragma unroll
        for (int ty = 0; ty < 3; ++ty)
            #pragma unroll
            for (int tx = 0; tx < 3; ++tx) {
                short8 ahi[2], alo[2];
                #pragma unroll
                for (int mt = 0; mt < 2; ++mt) {
                    int qe = ((2 * mh + mt + ty) * 18 + (l15 + tx)) * 32 + quad * 8;
                    ahi[mt] = *(const short8*)&Qs[qe];
                    alo[mt] = *(const short8*)&Qs[3456 + qe];
                }
                #pragma unroll
                for (int lxo = 0; lxo < 3; ++lxo) {
                    int ke = (nh + ty) * 3200 + (lxo * 16 + l15 + tx) * 32 + quad * 8;
                    short8 bhi = *(const short8*)&kc[ke];
                    short8 blo = *(const short8*)&kc[ke + 1600];
                    #pragma unroll
                    for (int mt = 0; mt < 2; ++mt) {
                        f32x4 s = sf[mt * 3 + lxo];
                        s = __builtin_amdgcn_mfma_f32_16x16x32_bf16(ahi[mt], bhi, s, 0, 0, 0);
                        s = __builtin_amdgcn_mfma_f32_16x16x32_bf16(ahi[mt], blo, s, 0, 0, 0);
                        s = __builtin_amdgcn_mfma_f32_16x16x32_bf16(alo[mt], bhi, s, 0, 0, 0);
                        sf[mt * 3 + lxo] = s;
                    }
                }
            }

        float invs[3];
        #pragma unroll
        for (int lxo = 0; lxo < 3; ++lxo)
            invs[lxo] = invb[(ly0 + nh) * 48 + lxo * 16 + l15];

        __syncthreads();   // A: previous PV done reading Pl

        // ---- p = exp(s*invs) -> Pl (tiled layout); accumulate l in regs
        #pragma unroll
        for (int mt = 0; mt < 2; ++mt)
            #pragma unroll
            for (int lxo = 0; lxo < 3; ++lxo) {
                int k = nh * 48 + lxo * 16 + l15;
                int base = ((2 * mh + mt) * 3 + (k >> 5)) * 512 + (k & 31);
                #pragma unroll
                for (int r = 0; r < 4; ++r) {
                    float p = __expf(sf[mt * 3 + lxo][r] * invs[lxo]);
                    u16 h = f2bf(p);
                    Pl[base + (quad * 4 + r) * 32] = h;
                    lacc[mt][r] += bf2f(h);   // l exactly as the PV MFMA sees P
                }
            }

        // stage next K slab (dbuf)
        if (it < 23) {
            #pragma unroll
            for (int j = 0; j < 6; ++j)
                *(short8*)&Ks[(it + 1) & 1][(tid + j * 256) * 8] = ktmp[j];
            if (tid < 64) *(short8*)&Ks[(it + 1) & 1][(tid + 1536) * 8] = ktmp[6];
        }
        __syncthreads();   // B: Pl + next Ks ready

        // ---- PV: O[64, this wave's 144 cols] += P[64,96] @ V[96,144]
        #pragma unroll
        for (int ks = 0; ks < 3; ++ks) {
            short8 pa[4];
            #pragma unroll
            for (int mt2 = 0; mt2 < 4; ++mt2)
                pa[mt2] = *(const short8*)&Pl[(mt2 * 3 + ks) * 512 + l15 * 32 + quad * 8];
            #pragma unroll
            for (int nt = 0; nt < 9; ++nt) {
                short8 vv = *(const short8*)(vw + (size_t)nt * 16 * 2304 + it * 96 + ks * 32);
                #pragma unroll
                for (int mt2 = 0; mt2 < 4; ++mt2)
                    acc[mt2 * 9 + nt] = __builtin_amdgcn_mfma_f32_16x16x32_bf16(pa[mt2], vv, acc[mt2 * 9 + nt], 0, 0, 0);
            }
        }
    }

    // ---- epilogue: sum lacc over l15, merge across nh waves, Z = O/(6l)
    #pragma unroll
    for (int mt = 0; mt < 2; ++mt)
        #pragma unroll
        for (int r = 0; r < 4; ++r) {
            float v = lacc[mt][r];
            v += __shfl_xor(v, 1);
            v += __shfl_xor(v, 2);
            v += __shfl_xor(v, 4);
            v += __shfl_xor(v, 8);
            lacc[mt][r] = v;
        }
    if (l15 == 0) {
        #pragma unroll
        for (int mt = 0; mt < 2; ++mt)
            #pragma unroll
            for (int r = 0; r < 4; ++r)
                llds[nh][(2 * mh + mt) * 16 + quad * 4 + r] = lacc[mt][r];
    }
    __syncthreads();
    float rli[4][4];
    #pragma unroll
    for (int mt2 = 0; mt2 < 4; ++mt2)
        #pragma unroll
        for (int r = 0; r < 4; ++r) {
            int m = mt2 * 16 + quad * 4 + r;
            rli[mt2][r] = 1.0f / ((llds[0][m] + llds[1][m]) * 6.0f);
        }

    float* Zb = Z + (size_t)brel * 9216 * 576;
    #pragma unroll
    for (int mt2 = 0; mt2 < 4; ++mt2) {
        int qrow = (py0 + mt2) * 96 + px0;
        #pragma unroll
        for (int r = 0; r < 4; ++r) {
            float rl = rli[mt2][r];
            float* zr = Zb + (size_t)(qrow + quad * 4 + r) * 576 + w * 144;
            #pragma unroll
            for (int nt = 0; nt < 9; ++nt)
                zr[nt * 16 + l15] = acc[mt2 * 9 + nt][r] * rl;
        }
    }
}

// ------------------------------------------------------------- gather (Z -> out)
__global__ void kgather(const float* __restrict__ Z, float* __restrict__ out, int b0) {
    __shared__ float zb[2 * 9 * 580];   // 41760 B
    int bi = blockIdx.x;                // nb*96*12
    int brel = bi / (96 * 12);
    int rem = bi % (96 * 12);
    int b = b0 + brel;
    int q = rem / 12, xt = rem % 12;
    int ox0 = xt * 16, p0 = ox0 >> 1;
    const float* Zb = Z + (size_t)brel * 9216 * 576;
    int tid = threadIdx.x;
    for (int id = tid; id < 2592; id += 256) {
        int pi = id / 1296, r2 = id % 1296;
        int pxi = r2 / 144, n4 = r2 % 144;
        int py = q + pi; if (py > 95) py = 95;
        int px = p0 + pxi; if (px > 95) px = 95;
        *(float4*)&zb[(pi * 9 + pxi) * 580 + n4 * 4] =
            *(const float4*)&Zb[(size_t)(py * 96 + px) * 576 + n4 * 4];
    }
    __syncthreads();
    int xi = tid & 15, cq = tid >> 4;
    int ox = ox0 + xi;
    bool oxv = ox <= 190;
    int ntx, txl[2], pxl[2];
    if (xi & 1) { ntx = 2; txl[0] = 0; pxl[0] = (xi + 1) >> 1; txl[1] = 2; pxl[1] = (xi - 1) >> 1; }
    else        { ntx = 1; txl[0] = 1; pxl[0] = xi >> 1; txl[1] = 1; pxl[1] = xi >> 1; }
    int oy0 = 2 * q;
    #pragma unroll
    for (int ck = 0; ck < 4; ++ck) {
        int c = cq + ck * 16;
        float v0 = 0.f, v1 = 0.f;
        for (int j = 0; j < ntx; ++j) {
            int tx = txl[j], pxi = pxl[j];
            v0 += zb[(0 * 9 + pxi) * 580 + (3 + tx) * 64 + c];
            v1 += zb[(1 * 9 + pxi) * 580 + (0 + tx) * 64 + c];
            v1 += zb[(0 * 9 + pxi) * 580 + (6 + tx) * 64 + c];
        }
        if (oxv) {
            float* o = out + (((size_t)(b * 64 + c) * 191 + oy0) * 191 + ox);
            *o = v0;
            if (q < 95) *(o + 191) = v1;
        }
    }
}

// --------------------------------------------------------------------- host
extern "C" void kernel_launch(void* const* d_in, const int* in_sizes, int n_in,
                              void* d_out, int out_size, void* d_ws, size_t ws_size,
                              hipStream_t stream) {
    const float* input = (const float*)d_in[0];
    const float* small = (const float*)d_in[1];
    const float* w1 = (const float*)d_in[2];
    const float* b1 = (const float*)d_in[3];
    const float* a1 = (const float*)d_in[4];
    const float* w2 = (const float*)d_in[5];
    const float* b2 = (const float*)d_in[6];
    const float* a2 = (const float*)d_in[7];
    const float* wa = (const float*)d_in[8];
    const float* ba = (const float*)d_in[9];
    const float* aa = (const float*)d_in[10];

    char* ws = (char*)d_ws;
    u16* xhi = (u16*)(ws + 0);              //  2,458,624
    u16* xlo = (u16*)(ws + 2458624);        //  2,458,624
    u16* rkl = (u16*)(ws + 4917248);        //  2,560,000
    float* ef = (float*)(ws + 7477248);     //  2,560,000
    u16* vtp = (u16*)(ws + 10037248);       // 10,616,832
    float* invn = (float*)(ws + 20654080);  //     36,864
    const size_t PREP = 20690944;
    float* Zbuf = (float*)(ws + PREP);      // nb*21,233,664
    float* out = (float*)d_out;

    int nb = (ws_size >= (size_t)105625600) ? 4 : 1;

    kzero<<<1024, 256, 0, stream>>>((float4*)ws, 10037248 / 16);
    kmatch<<<384, 256, 0, stream>>>(input, w1, b1, a1, xhi, xlo);
    ksmall<<<192, 256, 0, stream>>>(small, wa, ba, aa, w2, b2, a2, ef, rkl);
    kinvnorm<<<36, 256, 0, stream>>>(rkl, invn);
    kvtp<<<2048, 256, 0, stream>>>(ef, vtp);

    for (int b0 = 0; b0 < 4; b0 += nb) {
        kfused<<<nb * 144, 256, 0, stream>>>(xhi, xlo, rkl, vtp, invn, Zbuf, b0, nb);
        kgather<<<nb * 1152, 256, 0, stream>>>(Zbuf, out, b0);
    }
}

// Round 5
// 706.910 us; speedup vs baseline: 2.9466x; 1.1225x over previous
//
#include <hip/hip_runtime.h>

// CrossScaleAttention on MI355X — round 5.
// R4 post-mortem: fused kernel LDS-heavy + concurrency-starved (2 blk/CU,
// all pipes <20%); 60% of MFMA work was the bf16 hi/lo precision split.
// R5: (1) fp16 single-pass score (27 vs 162 MFMA/wave/iter; logit err ~1e-3),
// (2) Q frags in registers (zero A-frag LDS reads), single-buffered fp16 Ks,
// (3) BM=32 tiles + __launch_bounds__(256,3) -> 3 blk/CU, grid 1152/dispatch,
// XOR-swizzled P writes (2-way conflict = free), div-free kvtp.
//
// Workspace (101,246,976 B; known-good >= 105.6 MB):
//   xf16 : [4][98][98][32] fp16 match_input, zero halo        2,458,624
//   rkl  : [4][50][50][32] fp16 ref, zero halo                  640,000
//   ef32 : [4][50][50][64] f32 embed_w, zero halo             2,560,000
//   vtp  : [4][576][2304] bf16 V^T (n=tap*64+c, l=ly*48+lx)  10,616,832
//   invn : [4][2304] f32 10/max(norm,1e-4)                       36,864
//   Z    : [nb][9216][576] f32                            nb*21,233,664
// Fallback (ws < 101.2 MB): per-sample loop (37.5 MB).

typedef unsigned short u16;
typedef __attribute__((ext_vector_type(8))) short short8;      // 8 bf16
typedef __attribute__((ext_vector_type(8))) _Float16 half8;    // 8 fp16
typedef __attribute__((ext_vector_type(4))) float f32x4;

__device__ __forceinline__ u16 f2bf(float f) {
    unsigned u = __float_as_uint(f);
    unsigned r = (u + 0x7FFFu + ((u >> 16) & 1u)) >> 16;   // RNE
    return (u16)r;
}
__device__ __forceinline__ float bf2f(u16 h) {
    return __uint_as_float(((unsigned)h) << 16);
}
__device__ __forceinline__ u16 f2h(float f) {
    _Float16 h = (_Float16)f;           // v_cvt_f16_f32 (RNE)
    u16 u; __builtin_memcpy(&u, &h, 2); return u;
}
__device__ __forceinline__ float h2f(u16 u) {
    _Float16 h; __builtin_memcpy(&h, &u, 2); return (float)h;
}

// ---------------------------------------------------------------- zero fill
__global__ void kzero(float4* p, long n) {
    long i = (long)blockIdx.x * blockDim.x + threadIdx.x;
    long st = (long)gridDim.x * blockDim.x;
    float4 z; z.x = 0.f; z.y = 0.f; z.z = 0.f; z.w = 0.f;
    for (; i < n; i += st) p[i] = z;
}

// ------------------------------------------------- match_input -> xf16
__global__ void kmatch(const float* __restrict__ input, const float* __restrict__ w1,
                       const float* __restrict__ b1, const float* __restrict__ a1,
                       u16* __restrict__ xf16) {
    __shared__ float xl[64 * 96];
    __shared__ float wl[32 * 65];
    int b = blockIdx.x / 96, y = blockIdx.x % 96;
    int tid = threadIdx.x;
    for (int i = tid; i < 64 * 96; i += 256) {
        int ci = i / 96, xx = i % 96;
        xl[i] = input[(((b * 64 + ci) * 96) + y) * 96 + xx];
    }
    for (int i = tid; i < 2048; i += 256) wl[(i >> 6) * 65 + (i & 63)] = w1[i];
    __syncthreads();
    float aa = a1[0];
    for (int o = tid; o < 96 * 32; o += 256) {
        int xx = o >> 5, c = o & 31;
        float acc = b1[c];
        #pragma unroll
        for (int ci = 0; ci < 64; ci++) acc = fmaf(xl[ci * 96 + xx], wl[c * 65 + ci], acc);
        float v = acc >= 0.f ? acc : aa * acc;
        xf16[((b * 98 + y + 1) * 98 + (xx + 1)) * 32 + c] = f2h(v);
    }
}

// --------------------- small -> ef32 (embed, f32) + rkl fp16 (ref)
__global__ void ksmall(const float* __restrict__ small, const float* __restrict__ wasm,
                       const float* __restrict__ basm, const float* __restrict__ aasm,
                       const float* __restrict__ wm2, const float* __restrict__ bm2,
                       const float* __restrict__ am2,
                       float* __restrict__ ef32, u16* __restrict__ rkl) {
    __shared__ float sl[64 * 48];
    __shared__ float wa[64 * 65];
    __shared__ float wm[32 * 65];
    int b = blockIdx.x / 48, y = blockIdx.x % 48;
    int tid = threadIdx.x;
    for (int i = tid; i < 64 * 48; i += 256) {
        int ci = i / 48, xx = i % 48;
        sl[i] = small[(((b * 64 + ci) * 48) + y) * 48 + xx];
    }
    for (int i = tid; i < 4096; i += 256) wa[(i >> 6) * 65 + (i & 63)] = wasm[i];
    for (int i = tid; i < 2048; i += 256) wm[(i >> 6) * 65 + (i & 63)] = wm2[i];
    __syncthreads();
    float ae = aasm[0], ar = am2[0];
    for (int o = tid; o < 48 * 64; o += 256) {            // embed_w
        int xx = o >> 6, c = o & 63;
        float acc = basm[c];
        #pragma unroll
        for (int ci = 0; ci < 64; ci++) acc = fmaf(sl[ci * 48 + xx], wa[c * 65 + ci], acc);
        float v = acc >= 0.f ? acc : ae * acc;
        ef32[((b * 50 + y + 1) * 50 + (xx + 1)) * 64 + c] = v;
    }
    for (int o = tid; o < 48 * 32; o += 256) {            // ref -> rkl fp16
        int xx = o >> 5, c = o & 31;
        float acc = bm2[c];
        #pragma unroll
        for (int ci = 0; ci < 64; ci++) acc = fmaf(sl[ci * 48 + xx], wm[c * 65 + ci], acc);
        float v = acc >= 0.f ? acc : ar * acc;
        rkl[((b * 50 + y + 1) * 50 + (xx + 1)) * 32 + c] = f2h(v);
    }
}

// ------------------------------------------------------------ invnorm per key
__global__ void kinvnorm(const u16* __restrict__ rkl, float* __restrict__ invn) {
    int idx = blockIdx.x * 256 + threadIdx.x;   // 9216 exact
    int b = idx / 2304, l = idx % 2304;
    int ly = l / 48, lx = l % 48;
    float s = 0.f;
    for (int ty = 0; ty < 3; ty++)
        for (int tx = 0; tx < 3; tx++) {
            int base = ((b * 50 + ly + ty) * 50 + (lx + tx)) * 32;
            #pragma unroll
            for (int c = 0; c < 32; c++) {
                float v = h2f(rkl[base + c]);
                s = fmaf(v, v, s);
            }
        }
    invn[idx] = 10.f / fmaxf(sqrtf(s), 1e-4f);   // SCALE folded in
}

// ------------------------------------------------------------- pack V^T bf16
// grid = 4*576: one block per (b, n). Coalesced writes, div-free inner loop.
__global__ void kvtp(const float* __restrict__ ef32, u16* __restrict__ vtp) {
    int bi = blockIdx.x;
    int b = bi / 576, n = bi % 576;
    int t = n >> 6, c = n & 63;
    int ty = t / 3, tx = t % 3;
    const float* eb = ef32 + (size_t)b * 50 * 50 * 64 + c;
    u16* vo = vtp + (size_t)(b * 576 + n) * 2304;
    for (int l = threadIdx.x; l < 2304; l += 256) {
        int ly = l / 48, lx = l - ly * 48;
        vo[l] = f2bf(eb[((ly + ty) * 50 + (lx + tx)) * 64]);
    }
}

// ------------------------------------------------------------- fused score+PV
// grid = nb*288; block = 256 (4 waves: mh=w&1 -> M-tile, nh=w>>1 -> key half).
// BM=32 queries (2 py rows x 16 px), BN=96 keys/iter, 24 iters.
// Q frags in registers (loaded once from global). Ks single-buffered fp16
// (2 barriers/iter make dbuf unnecessary). Score = 1 fp16 MFMA per tap.
// P -> LDS tiled + XOR-swizzled (write conflicts 4-way -> 2-way = free).
// PV in bf16. l in regs, one LDS merge at end.
__launch_bounds__(256, 3)
__global__ void kfused2(const u16* __restrict__ xf16, const u16* __restrict__ rkl,
                        const u16* __restrict__ vtp, const float* __restrict__ invn,
                        float* __restrict__ Z, int b0, int nb) {
    __shared__ u16 Ks[6400];        // 12800 B: 4 halo rows x [50 px][32 c] fp16
    __shared__ u16 Pl[6 * 512];     //  6144 B: [(mt*3+kb)*512 + m*32 + kc^8*(m>>2)]
    __shared__ float llds[2][32];   //   256 B  -> 19200 B total

    int tid = threadIdx.x;
    int w = tid >> 6, lane = tid & 63, l15 = lane & 15, quad = lane >> 4;
    int mh = w & 1, nh = w >> 1;
    int bi = blockIdx.x, brel, t;
    if (nb == 4) { brel = bi & 3; t = bi >> 2; }
    else         { brel = 0; t = bi; }
    int b = b0 + brel;
    int px0 = (t % 6) * 16, pyb = (t / 6) * 2;

    const u16* xb = xf16 + (size_t)b * 98 * 98 * 32;
    const u16* rb = rkl + (size_t)b * 50 * 50 * 32;
    const float* invb = invn + b * 2304;
    const u16* vw = vtp + (size_t)b * 576 * 2304 + (size_t)(w * 144 + l15) * 2304 + quad * 8;

    // Q fragments in registers, loaded once (contiguous 1024 B per frag/wave)
    half8 qf[3][3];
    #pragma unroll
    for (int ty = 0; ty < 3; ++ty)
        #pragma unroll
        for (int tx = 0; tx < 3; ++tx)
            qf[ty][tx] = *(const half8*)(xb + (((pyb + mh + ty) * 98) + (px0 + l15 + tx)) * 32 + quad * 8);

    // stage Ks for iter 0 (800 short8 = 12800 B)
    {
        int i0 = tid, i1 = tid + 256, i2 = tid + 512, i3 = tid + 768;
        short8 t0 = *(const short8*)(rb + i0 * 8);
        short8 t1 = *(const short8*)(rb + i1 * 8);
        short8 t2 = *(const short8*)(rb + i2 * 8);
        short8 t3; bool h3 = i3 < 800;
        if (h3) t3 = *(const short8*)(rb + i3 * 8);
        *(short8*)&Ks[i0 * 8] = t0;
        *(short8*)&Ks[i1 * 8] = t1;
        *(short8*)&Ks[i2 * 8] = t2;
        if (h3) *(short8*)&Ks[i3 * 8] = t3;
    }

    f32x4 acc[18];
    #pragma unroll
    for (int i = 0; i < 18; i++) acc[i] = (f32x4)0.f;
    float lacc[4] = {0.f, 0.f, 0.f, 0.f};

    __syncthreads();

    for (int it = 0; it < 24; ++it) {
        int ly0 = it * 2;

        // ---- score: S[16 px of py row pyb+mh, 48 keys of row ly0+nh], fp16
        f32x4 sf[3];
        #pragma unroll
        for (int i = 0; i < 3; i++) sf[i] = (f32x4)0.f;
        #pragma unroll
        for (int ty = 0; ty < 3; ++ty)
            #pragma unroll
            for (int tx = 0; tx < 3; ++tx) {
                half8 a = qf[ty][tx];
                #pragma unroll
                for (int lxo = 0; lxo < 3; ++lxo) {
                    half8 bb = *(const half8*)&Ks[(nh + ty) * 1600 + (lxo * 16 + l15 + tx) * 32 + quad * 8];
                    sf[lxo] = __builtin_amdgcn_mfma_f32_16x16x32_f16(a, bb, sf[lxo], 0, 0, 0);
                }
            }

        float invs[3];
        #pragma unroll
        for (int lxo = 0; lxo < 3; ++lxo)
            invs[lxo] = invb[(ly0 + nh) * 48 + lxo * 16 + l15];

        __syncthreads();   // A: previous PV done reading Pl; score done reading Ks

        // ---- p = exp(s*invs) -> Pl (swizzled); accumulate l
        #pragma unroll
        for (int lxo = 0; lxo < 3; ++lxo) {
            int k = nh * 48 + lxo * 16 + l15;
            int kb = k >> 5;
            int kc = (k & 31) ^ (quad << 3);   // XOR swizzle by m>>2 (= quad)
            #pragma unroll
            for (int r = 0; r < 4; ++r) {
                float p = __expf(sf[lxo][r] * invs[lxo]);
                u16 h = f2bf(p);
                Pl[(mh * 3 + kb) * 512 + (quad * 4 + r) * 32 + kc] = h;
                lacc[r] += bf2f(h);   // l exactly as the PV MFMA sees P
            }
        }

        // ---- stage next Ks (single buffer is safe: all waves past score)
        if (it < 23) {
            const u16* src = rb + (ly0 + 2) * 1600;
            int i0 = tid, i1 = tid + 256, i2 = tid + 512, i3 = tid + 768;
            short8 t0 = *(const short8*)(src + i0 * 8);
            short8 t1 = *(const short8*)(src + i1 * 8);
            short8 t2 = *(const short8*)(src + i2 * 8);
            short8 t3; bool h3 = i3 < 800;
            if (h3) t3 = *(const short8*)(src + i3 * 8);
            *(short8*)&Ks[i0 * 8] = t0;
            *(short8*)&Ks[i1 * 8] = t1;
            *(short8*)&Ks[i2 * 8] = t2;
            if (h3) *(short8*)&Ks[i3 * 8] = t3;
        }
        __syncthreads();   // B: Pl + next Ks ready

        // ---- PV: O[32, this wave's 144 cols] += P[32,96] @ V[96,144], bf16
        #pragma unroll
        for (int ks = 0; ks < 3; ++ks) {
            short8 pa[2];
            #pragma unroll
            for (int mt = 0; mt < 2; ++mt)
                pa[mt] = *(const short8*)&Pl[(mt * 3 + ks) * 512 + l15 * 32 + ((quad ^ (l15 >> 2)) & 3) * 8];
            #pragma unroll
            for (int nt = 0; nt < 9; ++nt) {
                short8 vv = *(const short8*)(vw + (size_t)nt * 16 * 2304 + it * 96 + ks * 32);
                #pragma unroll
                for (int mt = 0; mt < 2; ++mt)
                    acc[mt * 9 + nt] = __builtin_amdgcn_mfma_f32_16x16x32_bf16(pa[mt], vv, acc[mt * 9 + nt], 0, 0, 0);
            }
        }
    }

    // ---- epilogue: reduce l over l15, merge nh halves, Z = O/(6l)
    #pragma unroll
    for (int r = 0; r < 4; ++r) {
        float v = lacc[r];
        v += __shfl_xor(v, 1);
        v += __shfl_xor(v, 2);
        v += __shfl_xor(v, 4);
        v += __shfl_xor(v, 8);
        lacc[r] = v;
    }
    if (l15 == 0) {
        #pragma unroll
        for (int r = 0; r < 4; ++r)
            llds[nh][mh * 16 + quad * 4 + r] = lacc[r];
    }
    __syncthreads();
    float rli[2][4];
    #pragma unroll
    for (int mt = 0; mt < 2; ++mt)
        #pragma unroll
        for (int r = 0; r < 4; ++r) {
            int m = mt * 16 + quad * 4 + r;
            rli[mt][r] = 1.0f / ((llds[0][m] + llds[1][m]) * 6.0f);
        }

    float* Zb = Z + (size_t)brel * 9216 * 576;
    #pragma unroll
    for (int mt = 0; mt < 2; ++mt) {
        #pragma unroll
        for (int r = 0; r < 4; ++r) {
            int q = (pyb + mt) * 96 + px0 + quad * 4 + r;
            float rl = rli[mt][r];
            float* zr = Zb + (size_t)q * 576 + w * 144;
            #pragma unroll
            for (int nt = 0; nt < 9; ++nt)
                zr[nt * 16 + l15] = acc[mt * 9 + nt][r] * rl;
        }
    }
}

// ------------------------------------------------------------- gather (Z -> out)
__global__ void kgather(const float* __restrict__ Z, float* __restrict__ out, int b0) {
    __shared__ float zb[2 * 9 * 580];   // 41760 B
    int bi = blockIdx.x;                // nb*96*12
    int brel = bi / (96 * 12);
    int rem = bi % (96 * 12);
    int b = b0 + brel;
    int q = rem / 12, xt = rem % 12;
    int ox0 = xt * 16, p0 = ox0 >> 1;
    const float* Zb = Z + (size_t)brel * 9216 * 576;
    int tid = threadIdx.x;
    for (int id = tid; id < 2592; id += 256) {
        int pi = id / 1296, r2 = id % 1296;
        int pxi = r2 / 144, n4 = r2 % 144;
        int py = q + pi; if (py > 95) py = 95;
        int px = p0 + pxi; if (px > 95) px = 95;
        *(float4*)&zb[(pi * 9 + pxi) * 580 + n4 * 4] =
            *(const float4*)&Zb[(size_t)(py * 96 + px) * 576 + n4 * 4];
    }
    __syncthreads();
    int xi = tid & 15, cq = tid >> 4;
    int ox = ox0 + xi;
    bool oxv = ox <= 190;
    int ntx, txl[2], pxl[2];
    if (xi & 1) { ntx = 2; txl[0] = 0; pxl[0] = (xi + 1) >> 1; txl[1] = 2; pxl[1] = (xi - 1) >> 1; }
    else        { ntx = 1; txl[0] = 1; pxl[0] = xi >> 1; txl[1] = 1; pxl[1] = xi >> 1; }
    int oy0 = 2 * q;
    #pragma unroll
    for (int ck = 0; ck < 4; ++ck) {
        int c = cq + ck * 16;
        float v0 = 0.f, v1 = 0.f;
        for (int j = 0; j < ntx; ++j) {
            int tx = txl[j], pxi = pxl[j];
            v0 += zb[(0 * 9 + pxi) * 580 + (3 + tx) * 64 + c];
            v1 += zb[(1 * 9 + pxi) * 580 + (0 + tx) * 64 + c];
            v1 += zb[(0 * 9 + pxi) * 580 + (6 + tx) * 64 + c];
        }
        if (oxv) {
            float* o = out + (((size_t)(b * 64 + c) * 191 + oy0) * 191 + ox);
            *o = v0;
            if (q < 95) *(o + 191) = v1;
        }
    }
}

// --------------------------------------------------------------------- host
extern "C" void kernel_launch(void* const* d_in, const int* in_sizes, int n_in,
                              void* d_out, int out_size, void* d_ws, size_t ws_size,
                              hipStream_t stream) {
    const float* input = (const float*)d_in[0];
    const float* small = (const float*)d_in[1];
    const float* w1 = (const float*)d_in[2];
    const float* b1 = (const float*)d_in[3];
    const float* a1 = (const float*)d_in[4];
    const float* w2 = (const float*)d_in[5];
    const float* b2 = (const float*)d_in[6];
    const float* a2 = (const float*)d_in[7];
    const float* wa = (const float*)d_in[8];
    const float* ba = (const float*)d_in[9];
    const float* aa = (const float*)d_in[10];

    char* ws = (char*)d_ws;
    u16* xf16 = (u16*)(ws + 0);             //  2,458,624
    u16* rkl = (u16*)(ws + 2458624);        //    640,000
    float* ef = (float*)(ws + 3098624);     //  2,560,000
    u16* vtp = (u16*)(ws + 5658624);        // 10,616,832
    float* invn = (float*)(ws + 16275456);  //     36,864
    const size_t PREP = 16312320;
    float* Zbuf = (float*)(ws + PREP);      // nb*21,233,664
    float* out = (float*)d_out;

    int nb = (ws_size >= (size_t)101246976) ? 4 : 1;

    kzero<<<1024, 256, 0, stream>>>((float4*)ws, 5658624 / 16);   // halo'd arrays
    kmatch<<<384, 256, 0, stream>>>(input, w1, b1, a1, xf16);
    ksmall<<<192, 256, 0, stream>>>(small, wa, ba, aa, w2, b2, a2, ef, rkl);
    kinvnorm<<<36, 256, 0, stream>>>(rkl, invn);
    kvtp<<<2304, 256, 0, stream>>>(ef, vtp);

    for (int b0 = 0; b0 < 4; b0 += nb) {
        kfused2<<<nb * 288, 256, 0, stream>>>(xf16, rkl, vtp, invn, Zbuf, b0, nb);
        kgather<<<nb * 1152, 256, 0, stream>>>(Zbuf, out, b0);
    }
}